// Round 12
// baseline (135.398 us; speedup 1.0000x reference)
//
#include <hip/hip_runtime.h>
#include <cstdint>
#include <cstddef>

// ---------- types ----------
typedef __attribute__((ext_vector_type(8))) __bf16 bf16x8;
typedef __attribute__((ext_vector_type(4))) float f32x4;

// fp32 -> bf16 round-to-nearest-even
__device__ __forceinline__ unsigned short f2bf(float x) {
    unsigned int u = __float_as_uint(x);
    u += 0x7fffu + ((u >> 16) & 1u);
    return (unsigned short)(u >> 16);
}

__device__ __forceinline__ ushort4 pack4bf(float a, float b, float c, float d) {
    union { ushort4 v; __bf16 e[4]; } u;
    u.e[0] = (__bf16)a; u.e[1] = (__bf16)b; u.e[2] = (__bf16)c; u.e[3] = (__bf16)d;
    return u.v;
}

typedef const __attribute__((address_space(1))) void* gptr_t;
typedef __attribute__((address_space(3))) void* lptr_t;
__device__ __forceinline__ void gload_lds16(const void* g, void* l) {
    __builtin_amdgcn_global_load_lds((gptr_t)g, (lptr_t)l, 16, 0, 0);
}

// ---------- cast x (fp32 -> bf16), 4 elems/thread, into d_out scratch ----------
__global__ __launch_bounds__(256) void cast_x_kernel(const float* __restrict__ x,
                                                     unsigned short* __restrict__ out) {
    int i = blockIdx.x * 256 + threadIdx.x;
    float4 v = ((const float4*)x)[i];
    ushort4 o;
    o.x = f2bf(v.x); o.y = f2bf(v.y); o.z = f2bf(v.z); o.w = f2bf(v.w);
    ((ushort4*)out)[i] = o;
}

// ---------- fused tiled transpose+cast of the 4 weight matrices ----------
__global__ __launch_bounds__(256) void transpose4_kernel(const float* __restrict__ W0,
                                                         const float* __restrict__ W1,
                                                         const float* __restrict__ W2,
                                                         const float* __restrict__ W3,
                                                         unsigned short* __restrict__ T0,
                                                         unsigned short* __restrict__ T1,
                                                         unsigned short* __restrict__ T2,
                                                         unsigned short* __restrict__ T3,
                                                         float s0) {
    __shared__ float Ts[64][65];
    const int D = 1024;
    const int m = blockIdx.z;
    const float* W = (m == 0) ? W0 : (m == 1) ? W1 : (m == 2) ? W2 : W3;
    unsigned short* T = (m == 0) ? T0 : (m == 1) ? T1 : (m == 2) ? T2 : T3;
    const float scale = (m == 0) ? s0 : 1.0f;
    const int kt = blockIdx.y * 64, nt = blockIdx.x * 64;
    const int tid = threadIdx.x;

    {
        const int r = tid >> 2, cs = (tid & 3) * 16;
#pragma unroll
        for (int j = 0; j < 16; j += 4) {
            f32x4 v = *(const f32x4*)&W[(size_t)(kt + r) * D + nt + cs + j];
#pragma unroll
            for (int e = 0; e < 4; ++e) Ts[r][cs + j + e] = v[e];
        }
    }
    __syncthreads();
    {
        const int n = tid >> 2, ks = (tid & 3) * 16;
        union { bf16x8 v[2]; __bf16 e[16]; } cv;
#pragma unroll
        for (int j = 0; j < 16; ++j) cv.e[j] = (__bf16)(Ts[ks + j][n] * scale);
        *(bf16x8*)&T[(size_t)(nt + n) * D + kt + ks] = cv.v[0];
        *(bf16x8*)&T[(size_t)(nt + n) * D + kt + ks + 8] = cv.v[1];
    }
}

// ---------- V transpose: Vt[bh][d][kv] = QKV[b*2048+kv][2048 + h*64 + d] ----------
__global__ __launch_bounds__(256) void vtrans_kernel(const unsigned short* __restrict__ QKV,
                                                     unsigned short* __restrict__ Vt) {
    __shared__ __align__(16) unsigned short Ts[64][72];
    const int S = 3072;
    const int kv0 = blockIdx.x * 64;
    const int bh = blockIdx.y;
    const int b = bh >> 4, h = bh & 15;
    const int tid = threadIdx.x;
    {
        const int r = tid >> 2, c = (tid & 3) * 16;
        const unsigned short* src = QKV + (size_t)(b * 2048 + kv0 + r) * S + 2048 + h * 64 + c;
        *(bf16x8*)&Ts[r][c] = *(const bf16x8*)src;
        *(bf16x8*)&Ts[r][c + 8] = *(const bf16x8*)(src + 8);
    }
    __syncthreads();
    {
        const int d = tid >> 2, kc = (tid & 3) * 16;
        union { bf16x8 v[2]; unsigned short e[16]; } cv;
#pragma unroll
        for (int j = 0; j < 16; ++j) cv.e[j] = Ts[kc + j][d];
        unsigned short* dst = Vt + (size_t)(bh * 64 + d) * 2048 + kv0 + kc;
        *(bf16x8*)&dst[0] = cv.v[0];
        *(bf16x8*)&dst[8] = cv.v[1];
    }
}

// ---------- GEMM, C = A * B with Bt = B^T given ----------
template <int OUTBF>
__global__ __launch_bounds__(256) void gemm_bt(const unsigned short* __restrict__ A,
                                               const unsigned short* __restrict__ Bt,
                                               void* __restrict__ Cout,
                                               int M, int N, int K, int lda, int ldc,
                                               int nbx) {
    __shared__ __align__(16) unsigned short Au[128 * 32];
    __shared__ __align__(16) unsigned short Bs[128 * 32];
    const int tid = threadIdx.x;
    const int w = tid >> 6;
    const int lane = tid & 63;

    const int nwg = gridDim.x;
    const int q8 = nwg >> 3;
    const int orig = blockIdx.x;
    const int newlin = (orig & 7) * q8 + (orig >> 3);
    const int by = newlin / nbx;
    const int bx = newlin - by * nbx;
    const int m0 = by * 128;
    const int n0 = bx * 128;
    const int wr = w >> 1, wc = w & 1;

    f32x4 acc[4][4];
#pragma unroll
    for (int i = 0; i < 4; ++i)
#pragma unroll
        for (int j = 0; j < 4; ++j) acc[i][j] = f32x4{0.f, 0.f, 0.f, 0.f};

    for (int kt = 0; kt < K; kt += 32) {
#pragma unroll
        for (int p = 0; p < 2; ++p) {
            int c = p * 4 + w;
            int row = c * 16 + (lane >> 2);
            gload_lds16(A + (size_t)(m0 + row) * lda + kt + (lane & 3) * 8,
                        &Au[c * 512]);
        }
#pragma unroll
        for (int p = 0; p < 2; ++p) {
            int c = p * 4 + w;
            int row = c * 16 + (lane >> 2);
            gload_lds16(Bt + (size_t)(n0 + row) * K + kt + (lane & 3) * 8,
                        &Bs[c * 512]);
        }
        __syncthreads();

        bf16x8 af[4], bfr[4];
#pragma unroll
        for (int m = 0; m < 4; ++m)
            af[m] = *(const bf16x8*)&Au[(wr * 64 + m * 16 + (lane & 15)) * 32 +
                                        (lane >> 4) * 8];
#pragma unroll
        for (int n = 0; n < 4; ++n)
            bfr[n] = *(const bf16x8*)&Bs[(wc * 64 + n * 16 + (lane & 15)) * 32 +
                                         (lane >> 4) * 8];
#pragma unroll
        for (int m = 0; m < 4; ++m)
#pragma unroll
            for (int n = 0; n < 4; ++n)
                acc[m][n] = __builtin_amdgcn_mfma_f32_16x16x32_bf16(af[m], bfr[n], acc[m][n], 0, 0, 0);
        __syncthreads();
    }

    const int crow = (lane >> 4) * 4;
    const int ccol = lane & 15;
#pragma unroll
    for (int m = 0; m < 4; ++m) {
#pragma unroll
        for (int n = 0; n < 4; ++n) {
            int r0 = m0 + wr * 64 + m * 16 + crow;
            int c0 = n0 + wc * 64 + n * 16 + ccol;
#pragma unroll
            for (int j = 0; j < 4; ++j) {
                if (OUTBF)
                    ((unsigned short*)Cout)[(size_t)(r0 + j) * ldc + c0] = f2bf(acc[m][n][j]);
                else
                    ((float*)Cout)[(size_t)(r0 + j) * ldc + c0] = acc[m][n][j];
            }
        }
    }
}

// ---------- causal flash attention (8-wave blocks, DMA-staged K/V^T) ----------
// QKV fused [B*L, 3072] bf16: Q cols [0,1024), K [1024,2048), V [2048,3072).
// Vt [bh][d=64][kv=2048] pre-transposed. Q pre-scaled by log2(e)/sqrt(hd).
// O written in-place over Q columns. Grid (32 bh, 16 qblk128), 512 threads:
// linear%8 = bh%8 (XCD locality), y -> 15-y heavy-first.
// Block = 128 q rows, 8 waves x 16 q each: per-wave cost identical to the
// 4-wave version but staging serves 2x rows (1 K-DMA + 1 V-DMA per thread)
// and LDS 51.2KB -> 3 blocks/CU (24 waves) for latency hiding.
// K/V^T staged via global_load_lds into LINEAR [row][64] LDS, global source
// pre-swizzled: chunk c_src = c ^ (row&7). Reads use x0/x1 = same XOR ->
// banks 4*(g^(qi&7)): 8 banks x 2-way = conflict-free.
__global__ __launch_bounds__(512) void flash_kernel(unsigned short* __restrict__ QKV,
                                                    const unsigned short* __restrict__ Vt) {
    __shared__ __align__(16) unsigned short Ks[2][64 * 64];
    __shared__ __align__(16) unsigned short Vs[2][64 * 64];
    __shared__ __align__(16) unsigned short Ps[8][16 * 72];

    const int tid = threadIdx.x;
    const int w = tid >> 6;             // 0..7
    const int lane = tid & 63;
    const int bh = blockIdx.x;          // XCD = bh % 8
    const int b = bh >> 4, h = bh & 15;
    const int rowbase = b * 2048;
    const int hd0 = h * 64;
    const int S = 3072;

    const int qi = lane & 15;           // lane's q column (softmax space)
    const int g = lane >> 4;            // lane group
    const int x0 = ((g ^ (qi & 7)) << 3);        // swizzled chunk offset, st=0
    const int x1 = (((g ^ 4) ^ (qi & 7)) << 3);  // st=1

    const int qblk = (15 - (int)blockIdx.y) * 128;
    const int q_start = qblk + w * 16;  // wave's first q row
    const int nt = qblk / 64 + 2;

    // staging: thread covers row r = tid>>3 (kv for K, d for V), chunk (tid&7),
    // source column pre-swizzled; dest is linear byte 16*tid.
    const int strow = tid >> 3;
    const int stch = (tid & 7) ^ (strow & 7);
    const unsigned short* gK = QKV + (size_t)(rowbase + strow) * S + 1024 + hd0 + stch * 8;
    const unsigned short* gV = Vt + (size_t)(bh * 64 + strow) * 2048 + stch * 8;

#define STAGE(buf)                                   \
    do {                                             \
        gload_lds16(gK, &Ks[buf][w * 512]);          \
        gload_lds16(gV, &Vs[buf][w * 512]);          \
        gK += 64 * S;                                \
        gV += 64;                                    \
    } while (0)

    // Q fragments (B-operand), 2 d-steps of 32 over hd=64
    bf16x8 qf[2];
#pragma unroll
    for (int st = 0; st < 2; ++st)
        qf[st] = *(const bf16x8*)(QKV + (size_t)(rowbase + q_start + qi) * S + hd0 +
                                  st * 32 + g * 8);

    float m_prev = -1e30f, lsum = 0.f;
    f32x4 oacc[4];
#pragma unroll
    for (int n = 0; n < 4; ++n) oacc[n] = f32x4{0.f, 0.f, 0.f, 0.f};

    STAGE(0);
    __syncthreads();   // drains vmcnt(0) before barrier

    int cur = 0;
    for (int t = 0; t < nt; ++t) {
        const int kv0 = t * 64;
        if (t + 1 < nt) STAGE(cur ^ 1);   // DMA into the other buffer

        // does this tile intersect this wave's causal range?
        if (kv0 <= q_start + 15) {
            const unsigned short* Kc = Ks[cur];
            const unsigned short* Vc = Vs[cur];

            // ---- S^T = K Q^T : sacc[n][j] = S[kv0 + n*16 + g*4 + j][q=qi] ----
            f32x4 sacc[4];
            __builtin_amdgcn_s_setprio(1);
#pragma unroll
            for (int n = 0; n < 4; ++n) {
                bf16x8 k0 = *(const bf16x8*)&Kc[(n * 16 + qi) * 64 + x0];
                bf16x8 k1 = *(const bf16x8*)&Kc[(n * 16 + qi) * 64 + x1];
                f32x4 c = f32x4{0.f, 0.f, 0.f, 0.f};
                c = __builtin_amdgcn_mfma_f32_16x16x32_bf16(k0, qf[0], c, 0, 0, 0);
                c = __builtin_amdgcn_mfma_f32_16x16x32_bf16(k1, qf[1], c, 0, 0, 0);
                sacc[n] = c;
            }
            __builtin_amdgcn_s_setprio(0);

            // ---- online softmax in exp2 domain (lane-local column q=qi) ----
            const bool diag = (kv0 + 64 > q_start);
            if (diag) {
                const int lim = q_start + qi - kv0;   // >= 0 for every lane (see note)
#pragma unroll
                for (int n = 0; n < 4; ++n)
#pragma unroll
                    for (int j = 0; j < 4; ++j)
                        if (n * 16 + g * 4 + j > lim) sacc[n][j] = -1e30f;
            }
            float tmax = -1e30f;
#pragma unroll
            for (int n = 0; n < 4; ++n) {
                float a = fmaxf(fmaxf(sacc[n][0], sacc[n][1]), fmaxf(sacc[n][2], sacc[n][3]));
                tmax = fmaxf(tmax, a);
            }
            tmax = fmaxf(tmax, __shfl_xor(tmax, 16));
            tmax = fmaxf(tmax, __shfl_xor(tmax, 32));

            const bool defer = __all(tmax - m_prev <= 8.0f);
            const float mnew = defer ? m_prev : fmaxf(m_prev, tmax);

            float psum = 0.f;
#pragma unroll
            for (int n = 0; n < 4; ++n) {
                float p0 = exp2f(sacc[n][0] - mnew);
                float p1 = exp2f(sacc[n][1] - mnew);
                float p2 = exp2f(sacc[n][2] - mnew);
                float p3 = exp2f(sacc[n][3] - mnew);
                psum += (p0 + p1) + (p2 + p3);
                *(ushort4*)&Ps[w][qi * 72 + n * 16 + g * 4] = pack4bf(p0, p1, p2, p3);
            }
            psum += __shfl_xor(psum, 16);
            psum += __shfl_xor(psum, 32);
            if (!defer) {
                float alpha = exp2f(m_prev - mnew);
                lsum *= alpha;
#pragma unroll
                for (int n = 0; n < 4; ++n)
#pragma unroll
                    for (int j = 0; j < 4; ++j) oacc[n][j] *= alpha;
                m_prev = mnew;
            }
            lsum += psum;

            // compile-time fence: Ps writes must precede the reads below
            asm volatile("" ::: "memory");

            // ---- O^T += V^T P^T ----
            __builtin_amdgcn_s_setprio(1);
#pragma unroll
            for (int st = 0; st < 2; ++st) {
                bf16x8 ptf = *(const bf16x8*)&Ps[w][qi * 72 + st * 32 + g * 8];
                const int xo = st ? x1 : x0;
#pragma unroll
                for (int n = 0; n < 4; ++n) {
                    bf16x8 vfr = *(const bf16x8*)&Vc[(n * 16 + qi) * 64 + xo];
                    oacc[n] = __builtin_amdgcn_mfma_f32_16x16x32_bf16(vfr, ptf, oacc[n], 0, 0, 0);
                }
            }
            __builtin_amdgcn_s_setprio(0);
        }
        __syncthreads();
        cur ^= 1;
    }
#undef STAGE

    // ---- normalize, transpose via Ps, coalesced O write over own Q rows ----
    {
        float inv = 1.0f / lsum;
#pragma unroll
        for (int n = 0; n < 4; ++n)
            *(ushort4*)&Ps[w][qi * 72 + n * 16 + g * 4] =
                pack4bf(oacc[n][0] * inv, oacc[n][1] * inv, oacc[n][2] * inv, oacc[n][3] * inv);
        asm volatile("" ::: "memory");
        const int r = lane >> 2;
        const int cs = (lane & 3) * 16;
        bf16x8 o0 = *(const bf16x8*)&Ps[w][r * 72 + cs];
        bf16x8 o1 = *(const bf16x8*)&Ps[w][r * 72 + cs + 8];
        *(bf16x8*)&QKV[(size_t)(rowbase + q_start + r) * S + hd0 + cs] = o0;
        *(bf16x8*)&QKV[(size_t)(rowbase + q_start + r) * S + hd0 + cs + 8] = o1;
    }
}

// ---------- launch ----------
extern "C" void kernel_launch(void* const* d_in, const int* in_sizes, int n_in,
                              void* d_out, int out_size, void* d_ws, size_t ws_size,
                              hipStream_t stream) {
    const float* x  = (const float*)d_in[0];
    const float* Wq = (const float*)d_in[1];
    const float* Wk = (const float*)d_in[2];
    const float* Wv = (const float*)d_in[3];
    const float* Wo = (const float*)d_in[4];
    float* out = (float*)d_out;

    const int WN = 1024 * 1024;
    const int XN = 4096 * 1024;

    // ws (32MB): Wqkv_t (6MB) + Wo_t (2MB) + QKV [4096][3072] (24MB).
    // d_out (16MB) doubles as scratch: [Xbf 8MB][Vt 8MB] — both dead before the
    // final O-projection overwrites d_out. Deterministic across replays.
    unsigned short* ws   = (unsigned short*)d_ws;
    unsigned short* Wqkv = ws;
    unsigned short* Wot  = Wqkv + 3 * WN;
    unsigned short* QKV  = Wot + WN;
    unsigned short* Xbf  = (unsigned short*)d_out;
    unsigned short* Vt   = Xbf + XN;

    cast_x_kernel<<<XN / 1024, 256, 0, stream>>>(x, Xbf);

    // Q scale: 1/sqrt(64) * log2(e)  (softmax in exp2 domain)
    transpose4_kernel<<<dim3(16, 16, 4), 256, 0, stream>>>(
        Wq, Wk, Wv, Wo, Wqkv, Wqkv + WN, Wqkv + 2 * WN, Wot, 0.125f * 1.4426950408889634f);

    // fused QKV projection: [4096,1024] x [1024,3072] -> [4096,3072]
    gemm_bt<1><<<24 * 32, 256, 0, stream>>>(
        Xbf, Wqkv, QKV, 4096, 3072, 1024, 1024, 3072, 24);

    // pre-transpose V: Vt[bh][d][kv]
    vtrans_kernel<<<dim3(32, 32), 256, 0, stream>>>(QKV, Vt);

    flash_kernel<<<dim3(32, 16), 512, 0, stream>>>(QKV, Vt);

    // output projection: A = O (bf16, Q region of QKV, lda=3072)
    gemm_bt<0><<<8 * 32, 256, 0, stream>>>(
        QKV, Wot, out, 4096, 1024, 1024, 3072, 1024, 8);
}

// Round 13
// 130.823 us; speedup vs baseline: 1.0350x; 1.0350x over previous
//
#include <hip/hip_runtime.h>
#include <cstdint>
#include <cstddef>

// ---------- types ----------
typedef __attribute__((ext_vector_type(8))) __bf16 bf16x8;
typedef __attribute__((ext_vector_type(4))) float f32x4;

// fp32 -> bf16 round-to-nearest-even
__device__ __forceinline__ unsigned short f2bf(float x) {
    unsigned int u = __float_as_uint(x);
    u += 0x7fffu + ((u >> 16) & 1u);
    return (unsigned short)(u >> 16);
}

__device__ __forceinline__ ushort4 pack4bf(float a, float b, float c, float d) {
    union { ushort4 v; __bf16 e[4]; } u;
    u.e[0] = (__bf16)a; u.e[1] = (__bf16)b; u.e[2] = (__bf16)c; u.e[3] = (__bf16)d;
    return u.v;
}

typedef const __attribute__((address_space(1))) void* gptr_t;
typedef __attribute__((address_space(3))) void* lptr_t;
__device__ __forceinline__ void gload_lds16(const void* g, void* l) {
    __builtin_amdgcn_global_load_lds((gptr_t)g, (lptr_t)l, 16, 0, 0);
}

// ---------- cast x (fp32 -> bf16), 4 elems/thread, into d_out scratch ----------
__global__ __launch_bounds__(256) void cast_x_kernel(const float* __restrict__ x,
                                                     unsigned short* __restrict__ out) {
    int i = blockIdx.x * 256 + threadIdx.x;
    float4 v = ((const float4*)x)[i];
    ushort4 o;
    o.x = f2bf(v.x); o.y = f2bf(v.y); o.z = f2bf(v.z); o.w = f2bf(v.w);
    ((ushort4*)out)[i] = o;
}

// ---------- fused tiled transpose+cast of the 4 weight matrices ----------
__global__ __launch_bounds__(256) void transpose4_kernel(const float* __restrict__ W0,
                                                         const float* __restrict__ W1,
                                                         const float* __restrict__ W2,
                                                         const float* __restrict__ W3,
                                                         unsigned short* __restrict__ T0,
                                                         unsigned short* __restrict__ T1,
                                                         unsigned short* __restrict__ T2,
                                                         unsigned short* __restrict__ T3,
                                                         float s0) {
    __shared__ float Ts[64][65];
    const int D = 1024;
    const int m = blockIdx.z;
    const float* W = (m == 0) ? W0 : (m == 1) ? W1 : (m == 2) ? W2 : W3;
    unsigned short* T = (m == 0) ? T0 : (m == 1) ? T1 : (m == 2) ? T2 : T3;
    const float scale = (m == 0) ? s0 : 1.0f;
    const int kt = blockIdx.y * 64, nt = blockIdx.x * 64;
    const int tid = threadIdx.x;

    {
        const int r = tid >> 2, cs = (tid & 3) * 16;
#pragma unroll
        for (int j = 0; j < 16; j += 4) {
            f32x4 v = *(const f32x4*)&W[(size_t)(kt + r) * D + nt + cs + j];
#pragma unroll
            for (int e = 0; e < 4; ++e) Ts[r][cs + j + e] = v[e];
        }
    }
    __syncthreads();
    {
        const int n = tid >> 2, ks = (tid & 3) * 16;
        union { bf16x8 v[2]; __bf16 e[16]; } cv;
#pragma unroll
        for (int j = 0; j < 16; ++j) cv.e[j] = (__bf16)(Ts[ks + j][n] * scale);
        *(bf16x8*)&T[(size_t)(nt + n) * D + kt + ks] = cv.v[0];
        *(bf16x8*)&T[(size_t)(nt + n) * D + kt + ks + 8] = cv.v[1];
    }
}

// ---------- GEMM, C = A * B with Bt = B^T given ----------
// A [M,K] bf16 row stride lda (global_load_lds), Bt [N,K] bf16 (stride K),
// C [M,N] row stride ldc (bf16 if OUTBF else f32). 128x128 tile, BK=32, 4 waves.
// 1D grid, bijective XCD-chunk swizzle (requires gridDim.x % 8 == 0).
// VT=1: blocks with n0 >= 2048 (the V projection) write TRANSPOSED to
// Vt[bh*64+d][kv] via per-wave LDS transpose (two 32-col passes), instead of
// writing into C. Eliminates the separate vtrans kernel.
template <int OUTBF, int VT>
__global__ __launch_bounds__(256) void gemm_bt(const unsigned short* __restrict__ A,
                                               const unsigned short* __restrict__ Bt,
                                               void* __restrict__ Cout,
                                               unsigned short* __restrict__ Vt,
                                               int M, int N, int K, int lda, int ldc,
                                               int nbx) {
    __shared__ __align__(16) unsigned short Au[128 * 32];
    __shared__ __align__(16) unsigned short Bs[128 * 32];
    const int tid = threadIdx.x;
    const int w = tid >> 6;
    const int lane = tid & 63;

    const int nwg = gridDim.x;
    const int q8 = nwg >> 3;
    const int orig = blockIdx.x;
    const int newlin = (orig & 7) * q8 + (orig >> 3);
    const int by = newlin / nbx;
    const int bx = newlin - by * nbx;
    const int m0 = by * 128;
    const int n0 = bx * 128;
    const int wr = w >> 1, wc = w & 1;

    f32x4 acc[4][4];
#pragma unroll
    for (int i = 0; i < 4; ++i)
#pragma unroll
        for (int j = 0; j < 4; ++j) acc[i][j] = f32x4{0.f, 0.f, 0.f, 0.f};

    for (int kt = 0; kt < K; kt += 32) {
#pragma unroll
        for (int p = 0; p < 2; ++p) {
            int c = p * 4 + w;
            int row = c * 16 + (lane >> 2);
            gload_lds16(A + (size_t)(m0 + row) * lda + kt + (lane & 3) * 8,
                        &Au[c * 512]);
        }
#pragma unroll
        for (int p = 0; p < 2; ++p) {
            int c = p * 4 + w;
            int row = c * 16 + (lane >> 2);
            gload_lds16(Bt + (size_t)(n0 + row) * K + kt + (lane & 3) * 8,
                        &Bs[c * 512]);
        }
        __syncthreads();

        bf16x8 af[4], bfr[4];
#pragma unroll
        for (int m = 0; m < 4; ++m)
            af[m] = *(const bf16x8*)&Au[(wr * 64 + m * 16 + (lane & 15)) * 32 +
                                        (lane >> 4) * 8];
#pragma unroll
        for (int n = 0; n < 4; ++n)
            bfr[n] = *(const bf16x8*)&Bs[(wc * 64 + n * 16 + (lane & 15)) * 32 +
                                         (lane >> 4) * 8];
#pragma unroll
        for (int m = 0; m < 4; ++m)
#pragma unroll
            for (int n = 0; n < 4; ++n)
                acc[m][n] = __builtin_amdgcn_mfma_f32_16x16x32_bf16(af[m], bfr[n], acc[m][n], 0, 0, 0);
        __syncthreads();
    }

    const int crow = (lane >> 4) * 4;
    const int ccol = lane & 15;

    if constexpr (VT) {
        if (n0 >= 2048) {
            // V projection block: per-wave 64x64 transpose through LDS, then
            // coalesced 64B writes to Vt[(b*16+h)*64 + d][kv].
            __shared__ __align__(16) unsigned short Tw[4][32 * 72];
            const int bb = m0 >> 11;                       // batch
            const int h = ((n0 - 2048) >> 6) + wc;         // head of this quadrant
            const int kvbase = (m0 & 2047) + wr * 64;      // quadrant kv origin
            unsigned short* vdst = Vt + (size_t)((bb * 16 + h) * 64) * 2048 + kvbase;
#pragma unroll
            for (int pass = 0; pass < 2; ++pass) {
                // stage quadrant cols [pass*32, pass*32+32) transposed: Tw[c][kv]
#pragma unroll
                for (int m = 0; m < 4; ++m)
#pragma unroll
                    for (int nn = 0; nn < 2; ++nn) {
                        int n = pass * 2 + nn;
                        int c = nn * 16 + ccol;            // 0..31
                        *(ushort4*)&Tw[w][c * 72 + m * 16 + crow] =
                            pack4bf(acc[m][n][0], acc[m][n][1], acc[m][n][2], acc[m][n][3]);
                    }
                asm volatile("" ::: "memory");   // DS in-order within wave
                // read back rows (d_loc) x 32 kv halves, write coalesced
                const int d_loc = lane >> 1;               // 0..31
                const int kvh = (lane & 1) * 32;
                unsigned short* dst = vdst + (size_t)(pass * 32 + d_loc) * 2048 + kvh;
#pragma unroll
                for (int i = 0; i < 4; ++i) {
                    bf16x8 v = *(const bf16x8*)&Tw[w][d_loc * 72 + kvh + i * 8];
                    *(bf16x8*)&dst[i * 8] = v;
                }
                asm volatile("" ::: "memory");   // WAR: pass1 writes after pass0 reads
            }
            return;
        }
    }

#pragma unroll
    for (int m = 0; m < 4; ++m) {
#pragma unroll
        for (int n = 0; n < 4; ++n) {
            int r0 = m0 + wr * 64 + m * 16 + crow;
            int c0 = n0 + wc * 64 + n * 16 + ccol;
#pragma unroll
            for (int j = 0; j < 4; ++j) {
                if (OUTBF)
                    ((unsigned short*)Cout)[(size_t)(r0 + j) * ldc + c0] = f2bf(acc[m][n][j]);
                else
                    ((float*)Cout)[(size_t)(r0 + j) * ldc + c0] = acc[m][n][j];
            }
        }
    }
}

// ---------- causal flash attention (r11 4-wave, DMA-staged K/V^T) ----------
// QKV fused [B*L, 3072] bf16: Q cols [0,1024), K [1024,2048), V region unused.
// Vt [bh][d=64][kv=2048] (written by the QKV GEMM's fused transpose epilogue).
// Q pre-scaled by log2(e)/sqrt(hd). O written in-place over Q columns.
// Grid (32 bh, 32 qblk): linear%8 = bh%8. K/V^T staged via global_load_lds
// into LINEAR [row][64] LDS with XOR-pre-swizzled global source (c^=row&7);
// reads x0/x1 apply the same XOR -> 8 banks x 2-way = conflict-free.
__global__ __launch_bounds__(256) void flash_kernel(unsigned short* __restrict__ QKV,
                                                    const unsigned short* __restrict__ Vt) {
    __shared__ __align__(16) unsigned short Ks[2][64 * 64];
    __shared__ __align__(16) unsigned short Vs[2][64 * 64];
    __shared__ __align__(16) unsigned short Ps[4][16 * 72];

    const int tid = threadIdx.x;
    const int w = tid >> 6;
    const int lane = tid & 63;
    const int bh = blockIdx.x;          // XCD = bh % 8
    const int b = bh >> 4, h = bh & 15;
    const int rowbase = b * 2048;
    const int hd0 = h * 64;
    const int S = 3072;

    const int qi = lane & 15;           // lane's q column (softmax space)
    const int g = lane >> 4;            // lane group
    const int x0 = ((g ^ (qi & 7)) << 3);        // swizzled chunk offset, st=0
    const int x1 = (((g ^ 4) ^ (qi & 7)) << 3);  // st=1

    const int qblk = (31 - (int)blockIdx.y) * 64;
    const int q0 = qblk + w * 16;
    const int nt = qblk / 64 + 1;
    const int q_rel = w * 16 + qi;

    // staging source pointers (pre-swizzled columns); advance per tile
    const unsigned short* gK[2];
    const unsigned short* gV[2];
#pragma unroll
    for (int p = 0; p < 2; ++p) {
        int row = p * 32 + w * 8 + (lane >> 3);       // kv for K, d for V
        int ch = (lane & 7) ^ (row & 7);
        gK[p] = QKV + (size_t)(rowbase + row) * S + 1024 + hd0 + ch * 8;
        gV[p] = Vt + (size_t)(bh * 64 + row) * 2048 + ch * 8;
    }

#define STAGE(buf)                                              \
    do {                                                        \
        gload_lds16(gK[0], &Ks[buf][w * 512]);                  \
        gload_lds16(gK[1], &Ks[buf][2048 + w * 512]);           \
        gload_lds16(gV[0], &Vs[buf][w * 512]);                  \
        gload_lds16(gV[1], &Vs[buf][2048 + w * 512]);           \
        gK[0] += 64 * S; gK[1] += 64 * S;                       \
        gV[0] += 64;     gV[1] += 64;                           \
    } while (0)

    // Q fragments (B-operand), 2 d-steps of 32 over hd=64
    bf16x8 qf[2];
#pragma unroll
    for (int st = 0; st < 2; ++st)
        qf[st] = *(const bf16x8*)(QKV + (size_t)(rowbase + q0 + qi) * S + hd0 +
                                  st * 32 + g * 8);

    float m_prev = -1e30f, lsum = 0.f;
    f32x4 oacc[4];
#pragma unroll
    for (int n = 0; n < 4; ++n) oacc[n] = f32x4{0.f, 0.f, 0.f, 0.f};

    STAGE(0);
    __syncthreads();   // drains vmcnt(0) before barrier

    int cur = 0;
    for (int t = 0; t < nt; ++t) {
        if (t + 1 < nt) STAGE(cur ^ 1);   // DMA into the other buffer

        const unsigned short* Kc = Ks[cur];
        const unsigned short* Vc = Vs[cur];

        // ---- S^T = K Q^T : sacc[n][j] = S[kv0 + n*16 + g*4 + j][q=qi] ----
        f32x4 sacc[4];
        __builtin_amdgcn_s_setprio(1);
#pragma unroll
        for (int n = 0; n < 4; ++n) {
            bf16x8 k0 = *(const bf16x8*)&Kc[(n * 16 + qi) * 64 + x0];
            bf16x8 k1 = *(const bf16x8*)&Kc[(n * 16 + qi) * 64 + x1];
            f32x4 c = f32x4{0.f, 0.f, 0.f, 0.f};
            c = __builtin_amdgcn_mfma_f32_16x16x32_bf16(k0, qf[0], c, 0, 0, 0);
            c = __builtin_amdgcn_mfma_f32_16x16x32_bf16(k1, qf[1], c, 0, 0, 0);
            sacc[n] = c;
        }
        __builtin_amdgcn_s_setprio(0);

        // ---- online softmax in exp2 domain (lane-local column q=qi) ----
        const bool diag = (t == nt - 1);
        if (diag) {
#pragma unroll
            for (int n = 0; n < 4; ++n)
#pragma unroll
                for (int j = 0; j < 4; ++j)
                    if (n * 16 + g * 4 + j > q_rel) sacc[n][j] = -1e30f;
        }
        float tmax = -1e30f;
#pragma unroll
        for (int n = 0; n < 4; ++n) {
            float a = fmaxf(fmaxf(sacc[n][0], sacc[n][1]), fmaxf(sacc[n][2], sacc[n][3]));
            tmax = fmaxf(tmax, a);
        }
        tmax = fmaxf(tmax, __shfl_xor(tmax, 16));
        tmax = fmaxf(tmax, __shfl_xor(tmax, 32));

        const bool defer = __all(tmax - m_prev <= 8.0f);
        const float mnew = defer ? m_prev : fmaxf(m_prev, tmax);

        float psum = 0.f;
#pragma unroll
        for (int n = 0; n < 4; ++n) {
            float p0 = exp2f(sacc[n][0] - mnew);
            float p1 = exp2f(sacc[n][1] - mnew);
            float p2 = exp2f(sacc[n][2] - mnew);
            float p3 = exp2f(sacc[n][3] - mnew);
            psum += (p0 + p1) + (p2 + p3);
            *(ushort4*)&Ps[w][qi * 72 + n * 16 + g * 4] = pack4bf(p0, p1, p2, p3);
        }
        psum += __shfl_xor(psum, 16);
        psum += __shfl_xor(psum, 32);
        if (!defer) {
            float alpha = exp2f(m_prev - mnew);
            lsum *= alpha;
#pragma unroll
            for (int n = 0; n < 4; ++n)
#pragma unroll
                for (int j = 0; j < 4; ++j) oacc[n][j] *= alpha;
            m_prev = mnew;
        }
        lsum += psum;

        // compile-time fence: Ps writes must precede the reads below
        asm volatile("" ::: "memory");

        // ---- O^T += V^T P^T ----
        __builtin_amdgcn_s_setprio(1);
#pragma unroll
        for (int st = 0; st < 2; ++st) {
            bf16x8 ptf = *(const bf16x8*)&Ps[w][qi * 72 + st * 32 + g * 8];
            const int xo = st ? x1 : x0;
#pragma unroll
            for (int n = 0; n < 4; ++n) {
                bf16x8 vfr = *(const bf16x8*)&Vc[(n * 16 + qi) * 64 + xo];
                oacc[n] = __builtin_amdgcn_mfma_f32_16x16x32_bf16(vfr, ptf, oacc[n], 0, 0, 0);
            }
        }
        __builtin_amdgcn_s_setprio(0);
        __syncthreads();
        cur ^= 1;
    }
#undef STAGE

    // ---- normalize, transpose via Ps, coalesced O write over own Q rows ----
    {
        float inv = 1.0f / lsum;
#pragma unroll
        for (int n = 0; n < 4; ++n)
            *(ushort4*)&Ps[w][qi * 72 + n * 16 + g * 4] =
                pack4bf(oacc[n][0] * inv, oacc[n][1] * inv, oacc[n][2] * inv, oacc[n][3] * inv);
        asm volatile("" ::: "memory");
        const int r = lane >> 2;
        const int cs = (lane & 3) * 16;
        bf16x8 o0 = *(const bf16x8*)&Ps[w][r * 72 + cs];
        bf16x8 o1 = *(const bf16x8*)&Ps[w][r * 72 + cs + 8];
        *(bf16x8*)&QKV[(size_t)(rowbase + q0 + r) * S + hd0 + cs] = o0;
        *(bf16x8*)&QKV[(size_t)(rowbase + q0 + r) * S + hd0 + cs + 8] = o1;
    }
}

// ---------- launch ----------
extern "C" void kernel_launch(void* const* d_in, const int* in_sizes, int n_in,
                              void* d_out, int out_size, void* d_ws, size_t ws_size,
                              hipStream_t stream) {
    const float* x  = (const float*)d_in[0];
    const float* Wq = (const float*)d_in[1];
    const float* Wk = (const float*)d_in[2];
    const float* Wv = (const float*)d_in[3];
    const float* Wo = (const float*)d_in[4];
    float* out = (float*)d_out;

    const int WN = 1024 * 1024;
    const int XN = 4096 * 1024;

    // ws (32MB): Wqkv_t (6MB) + Wo_t (2MB) + QKV [4096][3072] (24MB).
    // d_out (16MB) doubles as scratch: [Xbf 8MB][Vt 8MB] — both dead before the
    // final O-projection overwrites d_out. Deterministic across replays.
    unsigned short* ws   = (unsigned short*)d_ws;
    unsigned short* Wqkv = ws;
    unsigned short* Wot  = Wqkv + 3 * WN;
    unsigned short* QKV  = Wot + WN;
    unsigned short* Xbf  = (unsigned short*)d_out;
    unsigned short* Vt   = Xbf + XN;

    cast_x_kernel<<<XN / 1024, 256, 0, stream>>>(x, Xbf);

    // Q scale: 1/sqrt(64) * log2(e)  (softmax in exp2 domain)
    transpose4_kernel<<<dim3(16, 16, 4), 256, 0, stream>>>(
        Wq, Wk, Wv, Wo, Wqkv, Wqkv + WN, Wqkv + 2 * WN, Wot, 0.125f * 1.4426950408889634f);

    // fused QKV projection: [4096,1024] x [1024,3072] -> [4096,3072];
    // V-blocks write transposed into Vt (fused vtrans).
    gemm_bt<1, 1><<<24 * 32, 256, 0, stream>>>(
        Xbf, Wqkv, QKV, Vt, 4096, 3072, 1024, 1024, 3072, 24);

    flash_kernel<<<dim3(32, 32), 256, 0, stream>>>(QKV, Vt);

    // output projection: A = O (bf16, Q region of QKV, lda=3072)
    gemm_bt<0, 0><<<8 * 32, 256, 0, stream>>>(
        QKV, Wot, out, nullptr, 4096, 1024, 1024, 3072, 1024, 8);
}

// Round 14
// 111.357 us; speedup vs baseline: 1.2159x; 1.1748x over previous
//
#include <hip/hip_runtime.h>
#include <cstdint>
#include <cstddef>

// ---------- types ----------
typedef __attribute__((ext_vector_type(8))) __bf16 bf16x8;
typedef __attribute__((ext_vector_type(4))) float f32x4;

// fp32 -> bf16 round-to-nearest-even
__device__ __forceinline__ unsigned short f2bf(float x) {
    unsigned int u = __float_as_uint(x);
    u += 0x7fffu + ((u >> 16) & 1u);
    return (unsigned short)(u >> 16);
}

__device__ __forceinline__ ushort4 pack4bf(float a, float b, float c, float d) {
    union { ushort4 v; __bf16 e[4]; } u;
    u.e[0] = (__bf16)a; u.e[1] = (__bf16)b; u.e[2] = (__bf16)c; u.e[3] = (__bf16)d;
    return u.v;
}

typedef const __attribute__((address_space(1))) void* gptr_t;
typedef __attribute__((address_space(3))) void* lptr_t;
__device__ __forceinline__ void gload_lds16(const void* g, void* l) {
    __builtin_amdgcn_global_load_lds((gptr_t)g, (lptr_t)l, 16, 0, 0);
}

// ---------- cast x (fp32 -> bf16), 4 elems/thread, into d_out scratch ----------
__global__ __launch_bounds__(256) void cast_x_kernel(const float* __restrict__ x,
                                                     unsigned short* __restrict__ out) {
    int i = blockIdx.x * 256 + threadIdx.x;
    float4 v = ((const float4*)x)[i];
    ushort4 o;
    o.x = f2bf(v.x); o.y = f2bf(v.y); o.z = f2bf(v.z); o.w = f2bf(v.w);
    ((ushort4*)out)[i] = o;
}

// ---------- fused tiled transpose+cast of the 4 weight matrices ----------
__global__ __launch_bounds__(256) void transpose4_kernel(const float* __restrict__ W0,
                                                         const float* __restrict__ W1,
                                                         const float* __restrict__ W2,
                                                         const float* __restrict__ W3,
                                                         unsigned short* __restrict__ T0,
                                                         unsigned short* __restrict__ T1,
                                                         unsigned short* __restrict__ T2,
                                                         unsigned short* __restrict__ T3,
                                                         float s0) {
    __shared__ float Ts[64][65];
    const int D = 1024;
    const int m = blockIdx.z;
    const float* W = (m == 0) ? W0 : (m == 1) ? W1 : (m == 2) ? W2 : W3;
    unsigned short* T = (m == 0) ? T0 : (m == 1) ? T1 : (m == 2) ? T2 : T3;
    const float scale = (m == 0) ? s0 : 1.0f;
    const int kt = blockIdx.y * 64, nt = blockIdx.x * 64;
    const int tid = threadIdx.x;

    {
        const int r = tid >> 2, cs = (tid & 3) * 16;
#pragma unroll
        for (int j = 0; j < 16; j += 4) {
            f32x4 v = *(const f32x4*)&W[(size_t)(kt + r) * D + nt + cs + j];
#pragma unroll
            for (int e = 0; e < 4; ++e) Ts[r][cs + j + e] = v[e];
        }
    }
    __syncthreads();
    {
        const int n = tid >> 2, ks = (tid & 3) * 16;
        union { bf16x8 v[2]; __bf16 e[16]; } cv;
#pragma unroll
        for (int j = 0; j < 16; ++j) cv.e[j] = (__bf16)(Ts[ks + j][n] * scale);
        *(bf16x8*)&T[(size_t)(nt + n) * D + kt + ks] = cv.v[0];
        *(bf16x8*)&T[(size_t)(nt + n) * D + kt + ks + 8] = cv.v[1];
    }
}

// ---------- GEMM, C = A * B with Bt = B^T given ----------
// A [M,K] bf16 row stride lda, Bt [N,K] bf16 (stride K), C [M,N] stride ldc.
// 128x128 tile, BK=64, 4 waves. LDS tiles staged via global_load_lds with
// XOR-pre-swizzled source (chunk c_src = c ^ (row&7), 16B chunks); fragment
// reads apply the same XOR -> banks 4*(ch^(fq&7)): 8 groups x 2-way = free
// (was an 8-way conflict at BK=32 linear). BK=64 also halves barrier count.
// 1D grid, bijective XCD-chunk swizzle (requires gridDim.x % 8 == 0).
// VT=1: blocks with n0 >= 2048 (V projection) write TRANSPOSED to Vt.
template <int OUTBF, int VT>
__global__ __launch_bounds__(256) void gemm_bt(const unsigned short* __restrict__ A,
                                               const unsigned short* __restrict__ Bt,
                                               void* __restrict__ Cout,
                                               unsigned short* __restrict__ Vt,
                                               int M, int N, int K, int lda, int ldc,
                                               int nbx) {
    __shared__ __align__(16) unsigned short Au[128 * 64];
    __shared__ __align__(16) unsigned short Bs[128 * 64];
    const int tid = threadIdx.x;
    const int w = tid >> 6;
    const int lane = tid & 63;

    const int nwg = gridDim.x;
    const int q8 = nwg >> 3;
    const int orig = blockIdx.x;
    const int newlin = (orig & 7) * q8 + (orig >> 3);
    const int by = newlin / nbx;
    const int bx = newlin - by * nbx;
    const int m0 = by * 128;
    const int n0 = bx * 128;
    const int wr = w >> 1, wc = w & 1;

    f32x4 acc[4][4];
#pragma unroll
    for (int i = 0; i < 4; ++i)
#pragma unroll
        for (int j = 0; j < 4; ++j) acc[i][j] = f32x4{0.f, 0.f, 0.f, 0.f};

    // staging geometry: thread covers rows {p*32 + (tid>>3)}, chunk (tid&7),
    // source chunk pre-swizzled by row&7; dest is linear chunk p*256+tid.
    const int srow = tid >> 3;                       // 0..31
    const int sch = (tid & 7) ^ (srow & 7);          // row&7 == srow&7 for all p

    // fragment read offsets (elems): chunk (sub*4+fg) ^ (fq&7)
    const int fq = lane & 15, fg = lane >> 4;
    const int xa0 = ((fg ^ (fq & 7)) << 3);
    const int xa1 = (((fg ^ 4) ^ (fq & 7)) << 3);

    for (int kt = 0; kt < K; kt += 64) {
#pragma unroll
        for (int p = 0; p < 4; ++p) {
            gload_lds16(A + (size_t)(m0 + p * 32 + srow) * lda + kt + sch * 8,
                        &Au[(p * 256 + w * 64) * 8]);
            gload_lds16(Bt + (size_t)(n0 + p * 32 + srow) * K + kt + sch * 8,
                        &Bs[(p * 256 + w * 64) * 8]);
        }
        __syncthreads();

        bf16x8 af[4], bfr[4];
        // k-substep 0
#pragma unroll
        for (int m = 0; m < 4; ++m)
            af[m] = *(const bf16x8*)&Au[(wr * 64 + m * 16 + fq) * 64 + xa0];
#pragma unroll
        for (int n = 0; n < 4; ++n)
            bfr[n] = *(const bf16x8*)&Bs[(wc * 64 + n * 16 + fq) * 64 + xa0];
#pragma unroll
        for (int m = 0; m < 4; ++m)
#pragma unroll
            for (int n = 0; n < 4; ++n)
                acc[m][n] = __builtin_amdgcn_mfma_f32_16x16x32_bf16(af[m], bfr[n], acc[m][n], 0, 0, 0);
        // k-substep 1
#pragma unroll
        for (int m = 0; m < 4; ++m)
            af[m] = *(const bf16x8*)&Au[(wr * 64 + m * 16 + fq) * 64 + xa1];
#pragma unroll
        for (int n = 0; n < 4; ++n)
            bfr[n] = *(const bf16x8*)&Bs[(wc * 64 + n * 16 + fq) * 64 + xa1];
#pragma unroll
        for (int m = 0; m < 4; ++m)
#pragma unroll
            for (int n = 0; n < 4; ++n)
                acc[m][n] = __builtin_amdgcn_mfma_f32_16x16x32_bf16(af[m], bfr[n], acc[m][n], 0, 0, 0);
        __syncthreads();
    }

    const int crow = (lane >> 4) * 4;
    const int ccol = lane & 15;

    if constexpr (VT) {
        if (n0 >= 2048) {
            // V projection block: per-wave 64x64 transpose through LDS, then
            // coalesced 64B writes to Vt[(b*16+h)*64 + d][kv].
            __shared__ __align__(16) unsigned short Tw[4][32 * 72];
            const int bb = m0 >> 11;                       // batch
            const int h = ((n0 - 2048) >> 6) + wc;         // head of this quadrant
            const int kvbase = (m0 & 2047) + wr * 64;      // quadrant kv origin
            unsigned short* vdst = Vt + (size_t)((bb * 16 + h) * 64) * 2048 + kvbase;
#pragma unroll
            for (int pass = 0; pass < 2; ++pass) {
#pragma unroll
                for (int m = 0; m < 4; ++m)
#pragma unroll
                    for (int nn = 0; nn < 2; ++nn) {
                        int n = pass * 2 + nn;
                        int c = nn * 16 + ccol;            // 0..31
                        *(ushort4*)&Tw[w][c * 72 + m * 16 + crow] =
                            pack4bf(acc[m][n][0], acc[m][n][1], acc[m][n][2], acc[m][n][3]);
                    }
                asm volatile("" ::: "memory");   // DS in-order within wave
                const int d_loc = lane >> 1;               // 0..31
                const int kvh = (lane & 1) * 32;
                unsigned short* dst = vdst + (size_t)(pass * 32 + d_loc) * 2048 + kvh;
#pragma unroll
                for (int i = 0; i < 4; ++i) {
                    bf16x8 v = *(const bf16x8*)&Tw[w][d_loc * 72 + kvh + i * 8];
                    *(bf16x8*)&dst[i * 8] = v;
                }
                asm volatile("" ::: "memory");   // WAR: pass1 writes after pass0 reads
            }
            return;
        }
    }

#pragma unroll
    for (int m = 0; m < 4; ++m) {
#pragma unroll
        for (int n = 0; n < 4; ++n) {
            int r0 = m0 + wr * 64 + m * 16 + crow;
            int c0 = n0 + wc * 64 + n * 16 + ccol;
#pragma unroll
            for (int j = 0; j < 4; ++j) {
                if (OUTBF)
                    ((unsigned short*)Cout)[(size_t)(r0 + j) * ldc + c0] = f2bf(acc[m][n][j]);
                else
                    ((float*)Cout)[(size_t)(r0 + j) * ldc + c0] = acc[m][n][j];
            }
        }
    }
}

// ---------- causal flash attention (4-wave, DMA-staged K/V^T) ----------
// QKV fused [B*L, 3072] bf16: Q cols [0,1024), K [1024,2048), V region unused.
// Vt [bh][d=64][kv=2048] (written by the QKV GEMM's fused transpose epilogue).
// Q pre-scaled by log2(e)/sqrt(hd). O written in-place over Q columns.
// Grid (32 bh, 32 qblk): linear%8 = bh%8. K/V^T staged via global_load_lds
// into LINEAR [row][64] LDS with XOR-pre-swizzled global source (c^=row&7);
// reads x0/x1 apply the same XOR -> 8 banks x 2-way = conflict-free.
// Softmax: per-lane defer test (NO cross-lane shfl on the common path — the
// max reduction runs only on the rare rescale path); lsum kept as per-lane
// partial, reduced once in the epilogue.
__global__ __launch_bounds__(256) void flash_kernel(unsigned short* __restrict__ QKV,
                                                    const unsigned short* __restrict__ Vt) {
    __shared__ __align__(16) unsigned short Ks[2][64 * 64];
    __shared__ __align__(16) unsigned short Vs[2][64 * 64];
    __shared__ __align__(16) unsigned short Ps[4][16 * 72];

    const int tid = threadIdx.x;
    const int w = tid >> 6;
    const int lane = tid & 63;
    const int bh = blockIdx.x;          // XCD = bh % 8
    const int b = bh >> 4, h = bh & 15;
    const int rowbase = b * 2048;
    const int hd0 = h * 64;
    const int S = 3072;

    const int qi = lane & 15;           // lane's q column (softmax space)
    const int g = lane >> 4;            // lane group
    const int x0 = ((g ^ (qi & 7)) << 3);        // swizzled chunk offset, st=0
    const int x1 = (((g ^ 4) ^ (qi & 7)) << 3);  // st=1

    const int qblk = (31 - (int)blockIdx.y) * 64;
    const int q0 = qblk + w * 16;
    const int nt = qblk / 64 + 1;
    const int q_rel = w * 16 + qi;

    // staging source pointers (pre-swizzled columns); advance per tile
    const unsigned short* gK[2];
    const unsigned short* gV[2];
#pragma unroll
    for (int p = 0; p < 2; ++p) {
        int row = p * 32 + w * 8 + (lane >> 3);       // kv for K, d for V
        int ch = (lane & 7) ^ (row & 7);
        gK[p] = QKV + (size_t)(rowbase + row) * S + 1024 + hd0 + ch * 8;
        gV[p] = Vt + (size_t)(bh * 64 + row) * 2048 + ch * 8;
    }

#define STAGE(buf)                                              \
    do {                                                        \
        gload_lds16(gK[0], &Ks[buf][w * 512]);                  \
        gload_lds16(gK[1], &Ks[buf][2048 + w * 512]);           \
        gload_lds16(gV[0], &Vs[buf][w * 512]);                  \
        gload_lds16(gV[1], &Vs[buf][2048 + w * 512]);           \
        gK[0] += 64 * S; gK[1] += 64 * S;                       \
        gV[0] += 64;     gV[1] += 64;                           \
    } while (0)

    // Q fragments (B-operand), 2 d-steps of 32 over hd=64
    bf16x8 qf[2];
#pragma unroll
    for (int st = 0; st < 2; ++st)
        qf[st] = *(const bf16x8*)(QKV + (size_t)(rowbase + q0 + qi) * S + hd0 +
                                  st * 32 + g * 8);

    float m_prev = -1e30f, lsum = 0.f;   // lsum: PER-LANE partial (16 kv cols)
    f32x4 oacc[4];
#pragma unroll
    for (int n = 0; n < 4; ++n) oacc[n] = f32x4{0.f, 0.f, 0.f, 0.f};

    STAGE(0);
    __syncthreads();   // drains vmcnt(0) before barrier

    int cur = 0;
    for (int t = 0; t < nt; ++t) {
        if (t + 1 < nt) STAGE(cur ^ 1);   // DMA into the other buffer

        const unsigned short* Kc = Ks[cur];
        const unsigned short* Vc = Vs[cur];

        // ---- S^T = K Q^T : sacc[n][j] = S[kv0 + n*16 + g*4 + j][q=qi] ----
        f32x4 sacc[4];
        __builtin_amdgcn_s_setprio(1);
#pragma unroll
        for (int n = 0; n < 4; ++n) {
            bf16x8 k0 = *(const bf16x8*)&Kc[(n * 16 + qi) * 64 + x0];
            bf16x8 k1 = *(const bf16x8*)&Kc[(n * 16 + qi) * 64 + x1];
            f32x4 c = f32x4{0.f, 0.f, 0.f, 0.f};
            c = __builtin_amdgcn_mfma_f32_16x16x32_bf16(k0, qf[0], c, 0, 0, 0);
            c = __builtin_amdgcn_mfma_f32_16x16x32_bf16(k1, qf[1], c, 0, 0, 0);
            sacc[n] = c;
        }
        __builtin_amdgcn_s_setprio(0);

        // ---- online softmax in exp2 domain (lane-local column q=qi) ----
        const bool diag = (t == nt - 1);
        if (diag) {
#pragma unroll
            for (int n = 0; n < 4; ++n)
#pragma unroll
                for (int j = 0; j < 4; ++j)
                    if (n * 16 + g * 4 + j > q_rel) sacc[n][j] = -1e30f;
        }
        float tmax = -1e30f;   // per-lane max over this lane's 16 kv
#pragma unroll
        for (int n = 0; n < 4; ++n) {
            float a = fmaxf(fmaxf(sacc[n][0], sacc[n][1]), fmaxf(sacc[n][2], sacc[n][3]));
            tmax = fmaxf(tmax, a);
        }
        // defer test on per-lane partials: __all over partial maxes is
        // equivalent to __all over column maxes. No shfl on the common path.
        const bool defer = __all(tmax - m_prev <= 8.0f);
        float mcur = m_prev;
        if (!defer) {
            tmax = fmaxf(tmax, __shfl_xor(tmax, 16));
            tmax = fmaxf(tmax, __shfl_xor(tmax, 32));
            mcur = fmaxf(m_prev, tmax);
            float alpha = exp2f(m_prev - mcur);
            lsum *= alpha;     // alpha is column-consistent -> per-lane ok
#pragma unroll
            for (int n = 0; n < 4; ++n)
#pragma unroll
                for (int j = 0; j < 4; ++j) oacc[n][j] *= alpha;
            m_prev = mcur;
        }

        float psum = 0.f;
#pragma unroll
        for (int n = 0; n < 4; ++n) {
            float p0 = exp2f(sacc[n][0] - mcur);
            float p1 = exp2f(sacc[n][1] - mcur);
            float p2 = exp2f(sacc[n][2] - mcur);
            float p3 = exp2f(sacc[n][3] - mcur);
            psum += (p0 + p1) + (p2 + p3);
            *(ushort4*)&Ps[w][qi * 72 + n * 16 + g * 4] = pack4bf(p0, p1, p2, p3);
        }
        lsum += psum;   // per-lane partial; reduced in epilogue

        // compile-time fence: Ps writes must precede the reads below
        asm volatile("" ::: "memory");

        // ---- O^T += V^T P^T ----
        __builtin_amdgcn_s_setprio(1);
#pragma unroll
        for (int st = 0; st < 2; ++st) {
            bf16x8 ptf = *(const bf16x8*)&Ps[w][qi * 72 + st * 32 + g * 8];
            const int xo = st ? x1 : x0;
#pragma unroll
            for (int n = 0; n < 4; ++n) {
                bf16x8 vfr = *(const bf16x8*)&Vc[(n * 16 + qi) * 64 + xo];
                oacc[n] = __builtin_amdgcn_mfma_f32_16x16x32_bf16(vfr, ptf, oacc[n], 0, 0, 0);
            }
        }
        __builtin_amdgcn_s_setprio(0);
        __syncthreads();
        cur ^= 1;
    }
#undef STAGE

    // ---- reduce lsum across the column group, normalize, write O ----
    {
        lsum += __shfl_xor(lsum, 16);
        lsum += __shfl_xor(lsum, 32);
        float inv = 1.0f / lsum;
#pragma unroll
        for (int n = 0; n < 4; ++n)
            *(ushort4*)&Ps[w][qi * 72 + n * 16 + g * 4] =
                pack4bf(oacc[n][0] * inv, oacc[n][1] * inv, oacc[n][2] * inv, oacc[n][3] * inv);
        asm volatile("" ::: "memory");
        const int r = lane >> 2;
        const int cs = (lane & 3) * 16;
        bf16x8 o0 = *(const bf16x8*)&Ps[w][r * 72 + cs];
        bf16x8 o1 = *(const bf16x8*)&Ps[w][r * 72 + cs + 8];
        *(bf16x8*)&QKV[(size_t)(rowbase + q0 + r) * S + hd0 + cs] = o0;
        *(bf16x8*)&QKV[(size_t)(rowbase + q0 + r) * S + hd0 + cs + 8] = o1;
    }
}

// ---------- launch ----------
extern "C" void kernel_launch(void* const* d_in, const int* in_sizes, int n_in,
                              void* d_out, int out_size, void* d_ws, size_t ws_size,
                              hipStream_t stream) {
    const float* x  = (const float*)d_in[0];
    const float* Wq = (const float*)d_in[1];
    const float* Wk = (const float*)d_in[2];
    const float* Wv = (const float*)d_in[3];
    const float* Wo = (const float*)d_in[4];
    float* out = (float*)d_out;

    const int WN = 1024 * 1024;
    const int XN = 4096 * 1024;

    // ws (32MB): Wqkv_t (6MB) + Wo_t (2MB) + QKV [4096][3072] (24MB).
    // d_out (16MB) doubles as scratch: [Xbf 8MB][Vt 8MB] — both dead before the
    // final O-projection overwrites d_out. Deterministic across replays.
    unsigned short* ws   = (unsigned short*)d_ws;
    unsigned short* Wqkv = ws;
    unsigned short* Wot  = Wqkv + 3 * WN;
    unsigned short* QKV  = Wot + WN;
    unsigned short* Xbf  = (unsigned short*)d_out;
    unsigned short* Vt   = Xbf + XN;

    cast_x_kernel<<<XN / 1024, 256, 0, stream>>>(x, Xbf);

    // Q scale: 1/sqrt(64) * log2(e)  (softmax in exp2 domain)
    transpose4_kernel<<<dim3(16, 16, 4), 256, 0, stream>>>(
        Wq, Wk, Wv, Wo, Wqkv, Wqkv + WN, Wqkv + 2 * WN, Wot, 0.125f * 1.4426950408889634f);

    // fused QKV projection: [4096,1024] x [1024,3072] -> [4096,3072];
    // V-blocks write transposed into Vt (fused vtrans).
    gemm_bt<1, 1><<<24 * 32, 256, 0, stream>>>(
        Xbf, Wqkv, QKV, Vt, 4096, 3072, 1024, 1024, 3072, 24);

    flash_kernel<<<dim3(32, 32), 256, 0, stream>>>(QKV, Vt);

    // output projection: A = O (bf16, Q region of QKV, lda=3072)
    gemm_bt<0, 0><<<8 * 32, 256, 0, stream>>>(
        QKV, Wot, out, nullptr, 4096, 1024, 1024, 3072, 1024, 8);
}

// Round 15
// 105.151 us; speedup vs baseline: 1.2877x; 1.0590x over previous
//
#include <hip/hip_runtime.h>
#include <cstdint>
#include <cstddef>

// ---------- types ----------
typedef __attribute__((ext_vector_type(8))) __bf16 bf16x8;
typedef __attribute__((ext_vector_type(4))) float f32x4;

// fp32 -> bf16 round-to-nearest-even
__device__ __forceinline__ unsigned short f2bf(float x) {
    unsigned int u = __float_as_uint(x);
    u += 0x7fffu + ((u >> 16) & 1u);
    return (unsigned short)(u >> 16);
}

__device__ __forceinline__ ushort4 pack4bf(float a, float b, float c, float d) {
    union { ushort4 v; __bf16 e[4]; } u;
    u.e[0] = (__bf16)a; u.e[1] = (__bf16)b; u.e[2] = (__bf16)c; u.e[3] = (__bf16)d;
    return u.v;
}

// raw v_exp_f32 (single TRANS op) instead of guarded OCML exp2f
#if defined(__has_builtin)
#if __has_builtin(__builtin_amdgcn_exp2f)
#define EXP2(x) __builtin_amdgcn_exp2f(x)
#else
#define EXP2(x) exp2f(x)
#endif
#else
#define EXP2(x) exp2f(x)
#endif

typedef const __attribute__((address_space(1))) void* gptr_t;
typedef __attribute__((address_space(3))) void* lptr_t;
__device__ __forceinline__ void gload_lds16(const void* g, void* l) {
    __builtin_amdgcn_global_load_lds((gptr_t)g, (lptr_t)l, 16, 0, 0);
}

// ---------- cast x (fp32 -> bf16), 4 elems/thread, into d_out scratch ----------
__global__ __launch_bounds__(256) void cast_x_kernel(const float* __restrict__ x,
                                                     unsigned short* __restrict__ out) {
    int i = blockIdx.x * 256 + threadIdx.x;
    float4 v = ((const float4*)x)[i];
    ushort4 o;
    o.x = f2bf(v.x); o.y = f2bf(v.y); o.z = f2bf(v.z); o.w = f2bf(v.w);
    ((ushort4*)out)[i] = o;
}

// ---------- fused tiled transpose+cast of the 4 weight matrices ----------
__global__ __launch_bounds__(256) void transpose4_kernel(const float* __restrict__ W0,
                                                         const float* __restrict__ W1,
                                                         const float* __restrict__ W2,
                                                         const float* __restrict__ W3,
                                                         unsigned short* __restrict__ T0,
                                                         unsigned short* __restrict__ T1,
                                                         unsigned short* __restrict__ T2,
                                                         unsigned short* __restrict__ T3,
                                                         float s0) {
    __shared__ float Ts[64][65];
    const int D = 1024;
    const int m = blockIdx.z;
    const float* W = (m == 0) ? W0 : (m == 1) ? W1 : (m == 2) ? W2 : W3;
    unsigned short* T = (m == 0) ? T0 : (m == 1) ? T1 : (m == 2) ? T2 : T3;
    const float scale = (m == 0) ? s0 : 1.0f;
    const int kt = blockIdx.y * 64, nt = blockIdx.x * 64;
    const int tid = threadIdx.x;

    {
        const int r = tid >> 2, cs = (tid & 3) * 16;
#pragma unroll
        for (int j = 0; j < 16; j += 4) {
            f32x4 v = *(const f32x4*)&W[(size_t)(kt + r) * D + nt + cs + j];
#pragma unroll
            for (int e = 0; e < 4; ++e) Ts[r][cs + j + e] = v[e];
        }
    }
    __syncthreads();
    {
        const int n = tid >> 2, ks = (tid & 3) * 16;
        union { bf16x8 v[2]; __bf16 e[16]; } cv;
#pragma unroll
        for (int j = 0; j < 16; ++j) cv.e[j] = (__bf16)(Ts[ks + j][n] * scale);
        *(bf16x8*)&T[(size_t)(nt + n) * D + kt + ks] = cv.v[0];
        *(bf16x8*)&T[(size_t)(nt + n) * D + kt + ks + 8] = cv.v[1];
    }
}

// ---------- GEMM, C = A * B with Bt = B^T given ----------
// 128x128 tile, BK=64, 4 waves, XOR-pre-swizzled LDS (conflict-free frag reads).
// 1D grid, bijective XCD-chunk swizzle. VT=1: V-projection blocks (n0>=2048)
// write transposed to Vt via per-wave LDS transpose.
template <int OUTBF, int VT>
__global__ __launch_bounds__(256) void gemm_bt(const unsigned short* __restrict__ A,
                                               const unsigned short* __restrict__ Bt,
                                               void* __restrict__ Cout,
                                               unsigned short* __restrict__ Vt,
                                               int M, int N, int K, int lda, int ldc,
                                               int nbx) {
    __shared__ __align__(16) unsigned short Au[128 * 64];
    __shared__ __align__(16) unsigned short Bs[128 * 64];
    const int tid = threadIdx.x;
    const int w = tid >> 6;
    const int lane = tid & 63;

    const int nwg = gridDim.x;
    const int q8 = nwg >> 3;
    const int orig = blockIdx.x;
    const int newlin = (orig & 7) * q8 + (orig >> 3);
    const int by = newlin / nbx;
    const int bx = newlin - by * nbx;
    const int m0 = by * 128;
    const int n0 = bx * 128;
    const int wr = w >> 1, wc = w & 1;

    f32x4 acc[4][4];
#pragma unroll
    for (int i = 0; i < 4; ++i)
#pragma unroll
        for (int j = 0; j < 4; ++j) acc[i][j] = f32x4{0.f, 0.f, 0.f, 0.f};

    const int srow = tid >> 3;                       // 0..31
    const int sch = (tid & 7) ^ (srow & 7);

    const int fq = lane & 15, fg = lane >> 4;
    const int xa0 = ((fg ^ (fq & 7)) << 3);
    const int xa1 = (((fg ^ 4) ^ (fq & 7)) << 3);

    for (int kt = 0; kt < K; kt += 64) {
#pragma unroll
        for (int p = 0; p < 4; ++p) {
            gload_lds16(A + (size_t)(m0 + p * 32 + srow) * lda + kt + sch * 8,
                        &Au[(p * 256 + w * 64) * 8]);
            gload_lds16(Bt + (size_t)(n0 + p * 32 + srow) * K + kt + sch * 8,
                        &Bs[(p * 256 + w * 64) * 8]);
        }
        __syncthreads();

        bf16x8 af[4], bfr[4];
#pragma unroll
        for (int m = 0; m < 4; ++m)
            af[m] = *(const bf16x8*)&Au[(wr * 64 + m * 16 + fq) * 64 + xa0];
#pragma unroll
        for (int n = 0; n < 4; ++n)
            bfr[n] = *(const bf16x8*)&Bs[(wc * 64 + n * 16 + fq) * 64 + xa0];
#pragma unroll
        for (int m = 0; m < 4; ++m)
#pragma unroll
            for (int n = 0; n < 4; ++n)
                acc[m][n] = __builtin_amdgcn_mfma_f32_16x16x32_bf16(af[m], bfr[n], acc[m][n], 0, 0, 0);
#pragma unroll
        for (int m = 0; m < 4; ++m)
            af[m] = *(const bf16x8*)&Au[(wr * 64 + m * 16 + fq) * 64 + xa1];
#pragma unroll
        for (int n = 0; n < 4; ++n)
            bfr[n] = *(const bf16x8*)&Bs[(wc * 64 + n * 16 + fq) * 64 + xa1];
#pragma unroll
        for (int m = 0; m < 4; ++m)
#pragma unroll
            for (int n = 0; n < 4; ++n)
                acc[m][n] = __builtin_amdgcn_mfma_f32_16x16x32_bf16(af[m], bfr[n], acc[m][n], 0, 0, 0);
        __syncthreads();
    }

    const int crow = (lane >> 4) * 4;
    const int ccol = lane & 15;

    if constexpr (VT) {
        if (n0 >= 2048) {
            __shared__ __align__(16) unsigned short Tw[4][32 * 72];
            const int bb = m0 >> 11;
            const int h = ((n0 - 2048) >> 6) + wc;
            const int kvbase = (m0 & 2047) + wr * 64;
            unsigned short* vdst = Vt + (size_t)((bb * 16 + h) * 64) * 2048 + kvbase;
#pragma unroll
            for (int pass = 0; pass < 2; ++pass) {
#pragma unroll
                for (int m = 0; m < 4; ++m)
#pragma unroll
                    for (int nn = 0; nn < 2; ++nn) {
                        int n = pass * 2 + nn;
                        int c = nn * 16 + ccol;
                        *(ushort4*)&Tw[w][c * 72 + m * 16 + crow] =
                            pack4bf(acc[m][n][0], acc[m][n][1], acc[m][n][2], acc[m][n][3]);
                    }
                asm volatile("" ::: "memory");
                const int d_loc = lane >> 1;
                const int kvh = (lane & 1) * 32;
                unsigned short* dst = vdst + (size_t)(pass * 32 + d_loc) * 2048 + kvh;
#pragma unroll
                for (int i = 0; i < 4; ++i) {
                    bf16x8 v = *(const bf16x8*)&Tw[w][d_loc * 72 + kvh + i * 8];
                    *(bf16x8*)&dst[i * 8] = v;
                }
                asm volatile("" ::: "memory");
            }
            return;
        }
    }

#pragma unroll
    for (int m = 0; m < 4; ++m) {
#pragma unroll
        for (int n = 0; n < 4; ++n) {
            int r0 = m0 + wr * 64 + m * 16 + crow;
            int c0 = n0 + wc * 64 + n * 16 + ccol;
#pragma unroll
            for (int j = 0; j < 4; ++j) {
                if (OUTBF)
                    ((unsigned short*)Cout)[(size_t)(r0 + j) * ldc + c0] = f2bf(acc[m][n][j]);
                else
                    ((float*)Cout)[(size_t)(r0 + j) * ldc + c0] = acc[m][n][j];
            }
        }
    }
}

// ---------- causal flash attention (4-wave, K dbuf + V single-buffer) ----------
// QKV fused [B*L, 3072] bf16: Q cols [0,1024), K [1024,2048).
// Vt [bh][d=64][kv=2048] (from the QKV GEMM's fused transpose epilogue).
// Q pre-scaled by log2(e)/sqrt(hd). O written in-place over Q columns.
// Grid (32 bh, 32 qblk): linear%8 = bh%8. K/V^T staged via global_load_lds,
// XOR-pre-swizzled source (c^=row&7); reads x0/x1 same XOR -> conflict-free.
// V single-buffered: per tile [QK^T, softmax, barrier_A, PV, barrier_B,
// issue V(t+1) + K(t+2)]. barrier_A drains the DMAs issued one compute-phase
// earlier (QK^T+softmax covers the mostly-L2 latency). LDS 33.8KB -> 4 blk/CU.
// Softmax: per-lane defer test, lsum per-lane partial, exp via raw v_exp_f32.
__global__ __launch_bounds__(256) void flash_kernel(unsigned short* __restrict__ QKV,
                                                    const unsigned short* __restrict__ Vt) {
    __shared__ __align__(16) unsigned short Ks[2][64 * 64];
    __shared__ __align__(16) unsigned short Vs[64 * 64];
    __shared__ __align__(16) unsigned short Ps[4][16 * 72];

    const int tid = threadIdx.x;
    const int w = tid >> 6;
    const int lane = tid & 63;
    const int bh = blockIdx.x;          // XCD = bh % 8
    const int b = bh >> 4, h = bh & 15;
    const int rowbase = b * 2048;
    const int hd0 = h * 64;
    const int S = 3072;

    const int qi = lane & 15;           // lane's q column (softmax space)
    const int g = lane >> 4;            // lane group
    const int x0 = ((g ^ (qi & 7)) << 3);
    const int x1 = (((g ^ 4) ^ (qi & 7)) << 3);

    const int qblk = (31 - (int)blockIdx.y) * 64;
    const int q0 = qblk + w * 16;
    const int nt = qblk / 64 + 1;
    const int q_rel = w * 16 + qi;

    // staging source pointers (pre-swizzled columns); advance per tile
    const unsigned short* gK[2];
    const unsigned short* gV[2];
#pragma unroll
    for (int p = 0; p < 2; ++p) {
        int row = p * 32 + w * 8 + (lane >> 3);       // kv for K, d for V
        int ch = (lane & 7) ^ (row & 7);
        gK[p] = QKV + (size_t)(rowbase + row) * S + 1024 + hd0 + ch * 8;
        gV[p] = Vt + (size_t)(bh * 64 + row) * 2048 + ch * 8;
    }

#define STAGE_K(buf)                                            \
    do {                                                        \
        gload_lds16(gK[0], &Ks[buf][w * 512]);                  \
        gload_lds16(gK[1], &Ks[buf][2048 + w * 512]);           \
        gK[0] += 64 * S; gK[1] += 64 * S;                       \
    } while (0)
#define STAGE_V()                                               \
    do {                                                        \
        gload_lds16(gV[0], &Vs[w * 512]);                       \
        gload_lds16(gV[1], &Vs[2048 + w * 512]);                \
        gV[0] += 64; gV[1] += 64;                               \
    } while (0)

    // Q fragments (B-operand), 2 d-steps of 32 over hd=64
    bf16x8 qf[2];
#pragma unroll
    for (int st = 0; st < 2; ++st)
        qf[st] = *(const bf16x8*)(QKV + (size_t)(rowbase + q0 + qi) * S + hd0 +
                                  st * 32 + g * 8);

    float m_prev = -1e30f, lsum = 0.f;   // lsum: PER-LANE partial (16 kv cols)
    f32x4 oacc[4];
#pragma unroll
    for (int n = 0; n < 4; ++n) oacc[n] = f32x4{0.f, 0.f, 0.f, 0.f};

    STAGE_K(0);
    STAGE_V();
    if (nt > 1) STAGE_K(1);
    __syncthreads();   // drains vmcnt(0)

    for (int t = 0; t < nt; ++t) {
        const int cur = t & 1;
        const unsigned short* Kc = Ks[cur];

        // ---- S^T = K Q^T : sacc[n][j] = S[kv0 + n*16 + g*4 + j][q=qi] ----
        f32x4 sacc[4];
        __builtin_amdgcn_s_setprio(1);
#pragma unroll
        for (int n = 0; n < 4; ++n) {
            bf16x8 k0 = *(const bf16x8*)&Kc[(n * 16 + qi) * 64 + x0];
            bf16x8 k1 = *(const bf16x8*)&Kc[(n * 16 + qi) * 64 + x1];
            f32x4 c = f32x4{0.f, 0.f, 0.f, 0.f};
            c = __builtin_amdgcn_mfma_f32_16x16x32_bf16(k0, qf[0], c, 0, 0, 0);
            c = __builtin_amdgcn_mfma_f32_16x16x32_bf16(k1, qf[1], c, 0, 0, 0);
            sacc[n] = c;
        }
        __builtin_amdgcn_s_setprio(0);

        // ---- online softmax in exp2 domain (lane-local column q=qi) ----
        const bool diag = (t == nt - 1);
        if (diag) {
#pragma unroll
            for (int n = 0; n < 4; ++n)
#pragma unroll
                for (int j = 0; j < 4; ++j)
                    if (n * 16 + g * 4 + j > q_rel) sacc[n][j] = -1e30f;
        }
        float tmax = -1e30f;
#pragma unroll
        for (int n = 0; n < 4; ++n) {
            float a = fmaxf(fmaxf(sacc[n][0], sacc[n][1]), fmaxf(sacc[n][2], sacc[n][3]));
            tmax = fmaxf(tmax, a);
        }
        const bool defer = __all(tmax - m_prev <= 8.0f);
        float mcur = m_prev;
        if (!defer) {
            tmax = fmaxf(tmax, __shfl_xor(tmax, 16));
            tmax = fmaxf(tmax, __shfl_xor(tmax, 32));
            mcur = fmaxf(m_prev, tmax);
            float alpha = EXP2(m_prev - mcur);
            lsum *= alpha;
#pragma unroll
            for (int n = 0; n < 4; ++n)
#pragma unroll
                for (int j = 0; j < 4; ++j) oacc[n][j] *= alpha;
            m_prev = mcur;
        }

        float psum = 0.f;
#pragma unroll
        for (int n = 0; n < 4; ++n) {
            float p0 = EXP2(sacc[n][0] - mcur);
            float p1 = EXP2(sacc[n][1] - mcur);
            float p2 = EXP2(sacc[n][2] - mcur);
            float p3 = EXP2(sacc[n][3] - mcur);
            psum += (p0 + p1) + (p2 + p3);
            *(ushort4*)&Ps[w][qi * 72 + n * 16 + g * 4] = pack4bf(p0, p1, p2, p3);
        }
        lsum += psum;

        // compile-time fence: Ps writes must precede the reads below
        asm volatile("" ::: "memory");

        __syncthreads();   // barrier_A: V(t) landed (DMA issued one phase ago)

        // ---- O^T += V^T P^T ----
        __builtin_amdgcn_s_setprio(1);
#pragma unroll
        for (int st = 0; st < 2; ++st) {
            bf16x8 ptf = *(const bf16x8*)&Ps[w][qi * 72 + st * 32 + g * 8];
            const int xo = st ? x1 : x0;
#pragma unroll
            for (int n = 0; n < 4; ++n) {
                bf16x8 vfr = *(const bf16x8*)&Vs[(n * 16 + qi) * 64 + xo];
                oacc[n] = __builtin_amdgcn_mfma_f32_16x16x32_bf16(vfr, ptf, oacc[n], 0, 0, 0);
            }
        }
        __builtin_amdgcn_s_setprio(0);

        __syncthreads();   // barrier_B: all PV reads of Vs done
        if (t + 1 < nt) STAGE_V();       // V(t+1) -> Vs
        if (t + 2 < nt) STAGE_K(cur);    // K(t+2) -> Ks[cur] (reads done pre-A)
    }
#undef STAGE_K
#undef STAGE_V

    // ---- reduce lsum across the column group, normalize, write O ----
    {
        lsum += __shfl_xor(lsum, 16);
        lsum += __shfl_xor(lsum, 32);
        float inv = 1.0f / lsum;
#pragma unroll
        for (int n = 0; n < 4; ++n)
            *(ushort4*)&Ps[w][qi * 72 + n * 16 + g * 4] =
                pack4bf(oacc[n][0] * inv, oacc[n][1] * inv, oacc[n][2] * inv, oacc[n][3] * inv);
        asm volatile("" ::: "memory");
        const int r = lane >> 2;
        const int cs = (lane & 3) * 16;
        bf16x8 o0 = *(const bf16x8*)&Ps[w][r * 72 + cs];
        bf16x8 o1 = *(const bf16x8*)&Ps[w][r * 72 + cs + 8];
        *(bf16x8*)&QKV[(size_t)(rowbase + q0 + r) * S + hd0 + cs] = o0;
        *(bf16x8*)&QKV[(size_t)(rowbase + q0 + r) * S + hd0 + cs + 8] = o1;
    }
}

// ---------- launch ----------
extern "C" void kernel_launch(void* const* d_in, const int* in_sizes, int n_in,
                              void* d_out, int out_size, void* d_ws, size_t ws_size,
                              hipStream_t stream) {
    const float* x  = (const float*)d_in[0];
    const float* Wq = (const float*)d_in[1];
    const float* Wk = (const float*)d_in[2];
    const float* Wv = (const float*)d_in[3];
    const float* Wo = (const float*)d_in[4];
    float* out = (float*)d_out;

    const int WN = 1024 * 1024;
    const int XN = 4096 * 1024;

    // ws (32MB): Wqkv_t (6MB) + Wo_t (2MB) + QKV [4096][3072] (24MB).
    // d_out (16MB) doubles as scratch: [Xbf 8MB][Vt 8MB] — both dead before the
    // final O-projection overwrites d_out. Deterministic across replays.
    unsigned short* ws   = (unsigned short*)d_ws;
    unsigned short* Wqkv = ws;
    unsigned short* Wot  = Wqkv + 3 * WN;
    unsigned short* QKV  = Wot + WN;
    unsigned short* Xbf  = (unsigned short*)d_out;
    unsigned short* Vt   = Xbf + XN;

    cast_x_kernel<<<XN / 1024, 256, 0, stream>>>(x, Xbf);

    // Q scale: 1/sqrt(64) * log2(e)  (softmax in exp2 domain)
    transpose4_kernel<<<dim3(16, 16, 4), 256, 0, stream>>>(
        Wq, Wk, Wv, Wo, Wqkv, Wqkv + WN, Wqkv + 2 * WN, Wot, 0.125f * 1.4426950408889634f);

    // fused QKV projection: [4096,1024] x [1024,3072] -> [4096,3072];
    // V-blocks write transposed into Vt (fused vtrans).
    gemm_bt<1, 1><<<24 * 32, 256, 0, stream>>>(
        Xbf, Wqkv, QKV, Vt, 4096, 3072, 1024, 1024, 3072, 24);

    flash_kernel<<<dim3(32, 32), 256, 0, stream>>>(QKV, Vt);

    // output projection: A = O (bf16, Q region of QKV, lda=3072)
    gemm_bt<0, 0><<<8 * 32, 256, 0, stream>>>(
        QKV, Wot, out, nullptr, 4096, 1024, 1024, 3072, 1024, 8);
}

// Round 16
// 100.732 us; speedup vs baseline: 1.3441x; 1.0439x over previous
//
#include <hip/hip_runtime.h>
#include <cstdint>
#include <cstddef>

// ---------- types ----------
typedef __attribute__((ext_vector_type(8))) __bf16 bf16x8;
typedef __attribute__((ext_vector_type(4))) float f32x4;

// fp32 -> bf16 round-to-nearest-even
__device__ __forceinline__ unsigned short f2bf(float x) {
    unsigned int u = __float_as_uint(x);
    u += 0x7fffu + ((u >> 16) & 1u);
    return (unsigned short)(u >> 16);
}

__device__ __forceinline__ ushort4 pack4bf(float a, float b, float c, float d) {
    union { ushort4 v; __bf16 e[4]; } u;
    u.e[0] = (__bf16)a; u.e[1] = (__bf16)b; u.e[2] = (__bf16)c; u.e[3] = (__bf16)d;
    return u.v;
}

// raw v_exp_f32 (single TRANS op) instead of guarded OCML exp2f
#if defined(__has_builtin)
#if __has_builtin(__builtin_amdgcn_exp2f)
#define EXP2(x) __builtin_amdgcn_exp2f(x)
#else
#define EXP2(x) exp2f(x)
#endif
#else
#define EXP2(x) exp2f(x)
#endif

typedef const __attribute__((address_space(1))) void* gptr_t;
typedef __attribute__((address_space(3))) void* lptr_t;
__device__ __forceinline__ void gload_lds16(const void* g, void* l) {
    __builtin_amdgcn_global_load_lds((gptr_t)g, (lptr_t)l, 16, 0, 0);
}

// ---------- cast x (fp32 -> bf16), 4 elems/thread, into d_out scratch ----------
__global__ __launch_bounds__(256) void cast_x_kernel(const float* __restrict__ x,
                                                     unsigned short* __restrict__ out) {
    int i = blockIdx.x * 256 + threadIdx.x;
    float4 v = ((const float4*)x)[i];
    ushort4 o;
    o.x = f2bf(v.x); o.y = f2bf(v.y); o.z = f2bf(v.z); o.w = f2bf(v.w);
    ((ushort4*)out)[i] = o;
}

// ---------- fused tiled transpose+cast of the 4 weight matrices ----------
__global__ __launch_bounds__(256) void transpose4_kernel(const float* __restrict__ W0,
                                                         const float* __restrict__ W1,
                                                         const float* __restrict__ W2,
                                                         const float* __restrict__ W3,
                                                         unsigned short* __restrict__ T0,
                                                         unsigned short* __restrict__ T1,
                                                         unsigned short* __restrict__ T2,
                                                         unsigned short* __restrict__ T3,
                                                         float s0) {
    __shared__ float Ts[64][65];
    const int D = 1024;
    const int m = blockIdx.z;
    const float* W = (m == 0) ? W0 : (m == 1) ? W1 : (m == 2) ? W2 : W3;
    unsigned short* T = (m == 0) ? T0 : (m == 1) ? T1 : (m == 2) ? T2 : T3;
    const float scale = (m == 0) ? s0 : 1.0f;
    const int kt = blockIdx.y * 64, nt = blockIdx.x * 64;
    const int tid = threadIdx.x;

    {
        const int r = tid >> 2, cs = (tid & 3) * 16;
#pragma unroll
        for (int j = 0; j < 16; j += 4) {
            f32x4 v = *(const f32x4*)&W[(size_t)(kt + r) * D + nt + cs + j];
#pragma unroll
            for (int e = 0; e < 4; ++e) Ts[r][cs + j + e] = v[e];
        }
    }
    __syncthreads();
    {
        const int n = tid >> 2, ks = (tid & 3) * 16;
        union { bf16x8 v[2]; __bf16 e[16]; } cv;
#pragma unroll
        for (int j = 0; j < 16; ++j) cv.e[j] = (__bf16)(Ts[ks + j][n] * scale);
        *(bf16x8*)&T[(size_t)(nt + n) * D + kt + ks] = cv.v[0];
        *(bf16x8*)&T[(size_t)(nt + n) * D + kt + ks + 8] = cv.v[1];
    }
}

// ---------- GEMM, C = A * B with Bt = B^T given ----------
// 128 x (NBF*32) tile, BK=64, 4 waves (2x2), XOR-pre-swizzled LDS.
// NBF = n-fragments per wave (4 -> BN=128, 2 -> BN=64 for more blocks/CU).
// 1D grid, bijective XCD-chunk swizzle. VT=1 (NBF=4 only): V-projection
// blocks (n0>=2048) write transposed to Vt via per-wave LDS transpose.
template <int OUTBF, int VT, int NBF>
__global__ __launch_bounds__(256) void gemm_bt(const unsigned short* __restrict__ A,
                                               const unsigned short* __restrict__ Bt,
                                               void* __restrict__ Cout,
                                               unsigned short* __restrict__ Vt,
                                               int M, int N, int K, int lda, int ldc,
                                               int nbx) {
    static_assert(!VT || NBF == 4, "VT path requires NBF=4");
    __shared__ __align__(16) unsigned short Au[128 * 64];
    __shared__ __align__(16) unsigned short Bs[NBF * 32 * 64];
    const int tid = threadIdx.x;
    const int w = tid >> 6;
    const int lane = tid & 63;

    const int nwg = gridDim.x;
    const int q8 = nwg >> 3;
    const int orig = blockIdx.x;
    const int newlin = (orig & 7) * q8 + (orig >> 3);
    const int by = newlin / nbx;
    const int bx = newlin - by * nbx;
    const int m0 = by * 128;
    const int n0 = bx * (NBF * 32);
    const int wr = w >> 1, wc = w & 1;

    f32x4 acc[4][NBF];
#pragma unroll
    for (int i = 0; i < 4; ++i)
#pragma unroll
        for (int j = 0; j < NBF; ++j) acc[i][j] = f32x4{0.f, 0.f, 0.f, 0.f};

    const int srow = tid >> 3;                       // 0..31
    const int sch = (tid & 7) ^ (srow & 7);

    const int fq = lane & 15, fg = lane >> 4;
    const int xa0 = ((fg ^ (fq & 7)) << 3);
    const int xa1 = (((fg ^ 4) ^ (fq & 7)) << 3);

    for (int kt = 0; kt < K; kt += 64) {
#pragma unroll
        for (int p = 0; p < 4; ++p)
            gload_lds16(A + (size_t)(m0 + p * 32 + srow) * lda + kt + sch * 8,
                        &Au[(p * 256 + w * 64) * 8]);
#pragma unroll
        for (int p = 0; p < NBF; ++p)
            gload_lds16(Bt + (size_t)(n0 + p * 32 + srow) * K + kt + sch * 8,
                        &Bs[(p * 256 + w * 64) * 8]);
        __syncthreads();

        bf16x8 af[4], bfr[NBF];
#pragma unroll
        for (int m = 0; m < 4; ++m)
            af[m] = *(const bf16x8*)&Au[(wr * 64 + m * 16 + fq) * 64 + xa0];
#pragma unroll
        for (int n = 0; n < NBF; ++n)
            bfr[n] = *(const bf16x8*)&Bs[(wc * (NBF * 16) + n * 16 + fq) * 64 + xa0];
#pragma unroll
        for (int m = 0; m < 4; ++m)
#pragma unroll
            for (int n = 0; n < NBF; ++n)
                acc[m][n] = __builtin_amdgcn_mfma_f32_16x16x32_bf16(af[m], bfr[n], acc[m][n], 0, 0, 0);
#pragma unroll
        for (int m = 0; m < 4; ++m)
            af[m] = *(const bf16x8*)&Au[(wr * 64 + m * 16 + fq) * 64 + xa1];
#pragma unroll
        for (int n = 0; n < NBF; ++n)
            bfr[n] = *(const bf16x8*)&Bs[(wc * (NBF * 16) + n * 16 + fq) * 64 + xa1];
#pragma unroll
        for (int m = 0; m < 4; ++m)
#pragma unroll
            for (int n = 0; n < NBF; ++n)
                acc[m][n] = __builtin_amdgcn_mfma_f32_16x16x32_bf16(af[m], bfr[n], acc[m][n], 0, 0, 0);
        __syncthreads();
    }

    const int crow = (lane >> 4) * 4;
    const int ccol = lane & 15;

    if constexpr (VT) {
        if (n0 >= 2048) {
            __shared__ __align__(16) unsigned short Tw[4][32 * 72];
            const int bb = m0 >> 11;
            const int h = ((n0 - 2048) >> 6) + wc;
            const int kvbase = (m0 & 2047) + wr * 64;
            unsigned short* vdst = Vt + (size_t)((bb * 16 + h) * 64) * 2048 + kvbase;
#pragma unroll
            for (int pass = 0; pass < 2; ++pass) {
#pragma unroll
                for (int m = 0; m < 4; ++m)
#pragma unroll
                    for (int nn = 0; nn < 2; ++nn) {
                        int n = pass * 2 + nn;
                        int c = nn * 16 + ccol;
                        *(ushort4*)&Tw[w][c * 72 + m * 16 + crow] =
                            pack4bf(acc[m][n][0], acc[m][n][1], acc[m][n][2], acc[m][n][3]);
                    }
                asm volatile("" ::: "memory");
                const int d_loc = lane >> 1;
                const int kvh = (lane & 1) * 32;
                unsigned short* dst = vdst + (size_t)(pass * 32 + d_loc) * 2048 + kvh;
#pragma unroll
                for (int i = 0; i < 4; ++i) {
                    bf16x8 v = *(const bf16x8*)&Tw[w][d_loc * 72 + kvh + i * 8];
                    *(bf16x8*)&dst[i * 8] = v;
                }
                asm volatile("" ::: "memory");
            }
            return;
        }
    }

#pragma unroll
    for (int m = 0; m < 4; ++m) {
#pragma unroll
        for (int n = 0; n < NBF; ++n) {
            int r0 = m0 + wr * 64 + m * 16 + crow;
            int c0 = n0 + wc * (NBF * 16) + n * 16 + ccol;
#pragma unroll
            for (int j = 0; j < 4; ++j) {
                if (OUTBF)
                    ((unsigned short*)Cout)[(size_t)(r0 + j) * ldc + c0] = f2bf(acc[m][n][j]);
                else
                    ((float*)Cout)[(size_t)(r0 + j) * ldc + c0] = acc[m][n][j];
            }
        }
    }
}

// ---------- causal flash attention (rotated pipeline: QKT(t) || SM(t-1)) ----------
// QKV fused [B*L, 3072] bf16: Q cols [0,1024), K [1024,2048).
// Vt [bh][d=64][kv=2048] (from the QKV GEMM's fused transpose epilogue).
// Q pre-scaled by log2(e)/sqrt(hd). O written in-place over Q columns.
// Grid (32 bh, 32 qblk): linear%8 = bh%8. K/V^T staged via global_load_lds,
// XOR-pre-swizzled source; reads x0/x1 same XOR -> conflict-free.
// Loop rotation: iter t = { QKT(t)->snew [MFMA] || SM(t-1) on sprev [VALU]
// (register-independent -> scheduler interleaves), barA, PV(t-1), barB,
// stage V(t) + K(t+2), sprev=snew }. Diagonal masking happens ONLY in the
// epilogue SM (tile nt-1 is never SM'd in-loop). Hazards: V(t) staged at
// barB(t), drained barA(t+1)/epilogue sync, read by PV(t) in iter t+1;
// K(t+2) -> Ks[t&1] after QKT(t)'s reads retired; Ps same-wave DS order.
__global__ __launch_bounds__(256) void flash_kernel(unsigned short* __restrict__ QKV,
                                                    const unsigned short* __restrict__ Vt) {
    __shared__ __align__(16) unsigned short Ks[2][64 * 64];
    __shared__ __align__(16) unsigned short Vs[64 * 64];
    __shared__ __align__(16) unsigned short Ps[4][16 * 72];

    const int tid = threadIdx.x;
    const int w = tid >> 6;
    const int lane = tid & 63;
    const int bh = blockIdx.x;          // XCD = bh % 8
    const int b = bh >> 4, h = bh & 15;
    const int rowbase = b * 2048;
    const int hd0 = h * 64;
    const int S = 3072;

    const int qi = lane & 15;           // lane's q column (softmax space)
    const int g = lane >> 4;            // lane group
    const int x0 = ((g ^ (qi & 7)) << 3);
    const int x1 = (((g ^ 4) ^ (qi & 7)) << 3);

    const int qblk = (31 - (int)blockIdx.y) * 64;
    const int q0 = qblk + w * 16;
    const int nt = qblk / 64 + 1;
    const int q_rel = w * 16 + qi;

    const unsigned short* gK[2];
    const unsigned short* gV[2];
#pragma unroll
    for (int p = 0; p < 2; ++p) {
        int row = p * 32 + w * 8 + (lane >> 3);       // kv for K, d for V
        int ch = (lane & 7) ^ (row & 7);
        gK[p] = QKV + (size_t)(rowbase + row) * S + 1024 + hd0 + ch * 8;
        gV[p] = Vt + (size_t)(bh * 64 + row) * 2048 + ch * 8;
    }

#define STAGE_K(buf)                                            \
    do {                                                        \
        gload_lds16(gK[0], &Ks[buf][w * 512]);                  \
        gload_lds16(gK[1], &Ks[buf][2048 + w * 512]);           \
        gK[0] += 64 * S; gK[1] += 64 * S;                       \
    } while (0)
#define STAGE_V()                                               \
    do {                                                        \
        gload_lds16(gV[0], &Vs[w * 512]);                       \
        gload_lds16(gV[1], &Vs[2048 + w * 512]);                \
        gV[0] += 64; gV[1] += 64;                               \
    } while (0)

    bf16x8 qf[2];
#pragma unroll
    for (int st = 0; st < 2; ++st)
        qf[st] = *(const bf16x8*)(QKV + (size_t)(rowbase + q0 + qi) * S + hd0 +
                                  st * 32 + g * 8);

    float m_prev = -1e30f, lsum = 0.f;   // per-lane partials (16 kv cols)
    f32x4 oacc[4];
#pragma unroll
    for (int n = 0; n < 4; ++n) oacc[n] = f32x4{0.f, 0.f, 0.f, 0.f};
    f32x4 sprev[4], snew[4];

    STAGE_K(0);
    if (nt > 1) STAGE_K(1);
    __syncthreads();   // drains K(0), K(1)

    // softmax on sp (no masking) -> Ps, lsum, oacc rescale
#define SOFTMAX(sp)                                                            \
    do {                                                                       \
        float tmax = m_prev;                                                   \
        _Pragma("unroll")                                                      \
        for (int n = 0; n < 4; ++n) {                                          \
            tmax = fmaxf(fmaxf(tmax, sp[n][0]), sp[n][1]);                     \
            tmax = fmaxf(fmaxf(tmax, sp[n][2]), sp[n][3]);                     \
        }                                                                      \
        const bool defer = __all(tmax - m_prev <= 8.0f);                       \
        float mcur = m_prev;                                                   \
        if (!defer) {                                                          \
            tmax = fmaxf(tmax, __shfl_xor(tmax, 16));                          \
            tmax = fmaxf(tmax, __shfl_xor(tmax, 32));                          \
            mcur = tmax;                                                       \
            float alpha = EXP2(m_prev - mcur);                                 \
            lsum *= alpha;                                                     \
            _Pragma("unroll")                                                  \
            for (int n = 0; n < 4; ++n)                                        \
                _Pragma("unroll")                                              \
                for (int j = 0; j < 4; ++j) oacc[n][j] *= alpha;               \
            m_prev = mcur;                                                     \
        }                                                                      \
        float psum = 0.f;                                                      \
        _Pragma("unroll")                                                      \
        for (int n = 0; n < 4; ++n) {                                          \
            float p0 = EXP2(sp[n][0] - mcur);                                  \
            float p1 = EXP2(sp[n][1] - mcur);                                  \
            float p2 = EXP2(sp[n][2] - mcur);                                  \
            float p3 = EXP2(sp[n][3] - mcur);                                  \
            psum += (p0 + p1) + (p2 + p3);                                     \
            *(ushort4*)&Ps[w][qi * 72 + n * 16 + g * 4] = pack4bf(p0, p1, p2, p3); \
        }                                                                      \
        lsum += psum;                                                          \
    } while (0)

#define PV_STEP()                                                              \
    do {                                                                       \
        __builtin_amdgcn_s_setprio(1);                                         \
        _Pragma("unroll")                                                      \
        for (int st = 0; st < 2; ++st) {                                       \
            bf16x8 ptf = *(const bf16x8*)&Ps[w][qi * 72 + st * 32 + g * 8];    \
            const int xo = st ? x1 : x0;                                       \
            _Pragma("unroll")                                                  \
            for (int n = 0; n < 4; ++n) {                                      \
                bf16x8 vfr = *(const bf16x8*)&Vs[(n * 16 + qi) * 64 + xo];     \
                oacc[n] = __builtin_amdgcn_mfma_f32_16x16x32_bf16(vfr, ptf, oacc[n], 0, 0, 0); \
            }                                                                  \
        }                                                                      \
        __builtin_amdgcn_s_setprio(0);                                         \
    } while (0)

    for (int t = 0; t < nt; ++t) {
        const unsigned short* Kc = Ks[t & 1];

        // ---- QKT(t) -> snew (MFMA; independent of SM(t-1)'s VALU below) ----
        __builtin_amdgcn_s_setprio(1);
#pragma unroll
        for (int n = 0; n < 4; ++n) {
            bf16x8 k0 = *(const bf16x8*)&Kc[(n * 16 + qi) * 64 + x0];
            bf16x8 k1 = *(const bf16x8*)&Kc[(n * 16 + qi) * 64 + x1];
            f32x4 c = f32x4{0.f, 0.f, 0.f, 0.f};
            c = __builtin_amdgcn_mfma_f32_16x16x32_bf16(k0, qf[0], c, 0, 0, 0);
            c = __builtin_amdgcn_mfma_f32_16x16x32_bf16(k1, qf[1], c, 0, 0, 0);
            snew[n] = c;
        }
        __builtin_amdgcn_s_setprio(0);

        // ---- SM(t-1) on sprev (never the diagonal tile) ----
        if (t > 0) SOFTMAX(sprev);

        asm volatile("" ::: "memory");
        __syncthreads();   // barA: V(t-1) (and any pending K DMA) landed

        if (t > 0) PV_STEP();   // PV(t-1) on Vs

        __syncthreads();   // barB: Vs reads done
        STAGE_V();                       // V(t) -> Vs
        if (t + 2 < nt) STAGE_K(t & 1);  // K(t+2) -> Ks[t&1]

#pragma unroll
        for (int n = 0; n < 4; ++n) sprev[n] = snew[n];
    }
#undef STAGE_K
#undef STAGE_V

    // ---- epilogue: diagonal masking + SM + PV for tile nt-1 ----
    __syncthreads();   // drains V(nt-1)
#pragma unroll
    for (int n = 0; n < 4; ++n)
#pragma unroll
        for (int j = 0; j < 4; ++j)
            if (n * 16 + g * 4 + j > q_rel) sprev[n][j] = -1e30f;
    SOFTMAX(sprev);
    asm volatile("" ::: "memory");
    PV_STEP();
#undef SOFTMAX
#undef PV_STEP

    // ---- reduce lsum across the column group, normalize, write O ----
    {
        lsum += __shfl_xor(lsum, 16);
        lsum += __shfl_xor(lsum, 32);
        float inv = 1.0f / lsum;
#pragma unroll
        for (int n = 0; n < 4; ++n)
            *(ushort4*)&Ps[w][qi * 72 + n * 16 + g * 4] =
                pack4bf(oacc[n][0] * inv, oacc[n][1] * inv, oacc[n][2] * inv, oacc[n][3] * inv);
        asm volatile("" ::: "memory");
        const int r = lane >> 2;
        const int cs = (lane & 3) * 16;
        bf16x8 o0 = *(const bf16x8*)&Ps[w][r * 72 + cs];
        bf16x8 o1 = *(const bf16x8*)&Ps[w][r * 72 + cs + 8];
        *(bf16x8*)&QKV[(size_t)(rowbase + q0 + r) * S + hd0 + cs] = o0;
        *(bf16x8*)&QKV[(size_t)(rowbase + q0 + r) * S + hd0 + cs + 8] = o1;
    }
}

// ---------- launch ----------
extern "C" void kernel_launch(void* const* d_in, const int* in_sizes, int n_in,
                              void* d_out, int out_size, void* d_ws, size_t ws_size,
                              hipStream_t stream) {
    const float* x  = (const float*)d_in[0];
    const float* Wq = (const float*)d_in[1];
    const float* Wk = (const float*)d_in[2];
    const float* Wv = (const float*)d_in[3];
    const float* Wo = (const float*)d_in[4];
    float* out = (float*)d_out;

    const int WN = 1024 * 1024;
    const int XN = 4096 * 1024;

    // ws (32MB): Wqkv_t (6MB) + Wo_t (2MB) + QKV [4096][3072] (24MB).
    // d_out (16MB) doubles as scratch: [Xbf 8MB][Vt 8MB] — both dead before the
    // final O-projection overwrites d_out. Deterministic across replays.
    unsigned short* ws   = (unsigned short*)d_ws;
    unsigned short* Wqkv = ws;
    unsigned short* Wot  = Wqkv + 3 * WN;
    unsigned short* QKV  = Wot + WN;
    unsigned short* Xbf  = (unsigned short*)d_out;
    unsigned short* Vt   = Xbf + XN;

    cast_x_kernel<<<XN / 1024, 256, 0, stream>>>(x, Xbf);

    // Q scale: 1/sqrt(64) * log2(e)  (softmax in exp2 domain)
    transpose4_kernel<<<dim3(16, 16, 4), 256, 0, stream>>>(
        Wq, Wk, Wv, Wo, Wqkv, Wqkv + WN, Wqkv + 2 * WN, Wot, 0.125f * 1.4426950408889634f);

    // fused QKV projection: [4096,1024] x [1024,3072] -> [4096,3072];
    // V-blocks write transposed into Vt (fused vtrans).
    gemm_bt<1, 1, 4><<<24 * 32, 256, 0, stream>>>(
        Xbf, Wqkv, QKV, Vt, 4096, 3072, 1024, 1024, 3072, 24);

    flash_kernel<<<dim3(32, 32), 256, 0, stream>>>(QKV, Vt);

    // output projection: A = O (bf16, Q region of QKV, lda=3072), BN=64
    gemm_bt<0, 0, 2><<<16 * 32, 256, 0, stream>>>(
        QKV, Wot, out, nullptr, 4096, 1024, 1024, 3072, 1024, 16);
}